// Round 1
// baseline (986.436 us; speedup 1.0000x reference)
//
#include <hip/hip_runtime.h>
#include <hip/hip_bf16.h>
#include <stdint.h>

#define DIMC 512
#define NTOK 98
#define HD   32
// M_TOTAL = 1024*98 = 100352 = 784 * 128

typedef float f32x4 __attribute__((ext_vector_type(4)));
typedef short bf16x8 __attribute__((ext_vector_type(8)));

__device__ inline unsigned short f2bf(float f) {
    union { float f; uint32_t u; } v; v.f = f;
    uint32_t r = v.u + 0x7fffu + ((v.u >> 16) & 1u);
    return (unsigned short)(r >> 16);
}

__device__ inline bf16x8 cvt8(float4 a, float4 b) {
    bf16x8 r;
    r[0] = (short)f2bf(a.x); r[1] = (short)f2bf(a.y);
    r[2] = (short)f2bf(a.z); r[3] = (short)f2bf(a.w);
    r[4] = (short)f2bf(b.x); r[5] = (short)f2bf(b.y);
    r[6] = (short)f2bf(b.z); r[7] = (short)f2bf(b.w);
    return r;
}

// ---------------- bias gather: bias_full[h][i][j] = table[idx[i][j]*16 + h] ----
__global__ void k_bias(const float* __restrict__ table, const int* __restrict__ idx,
                       float* __restrict__ bias_full) {
    int h = blockIdx.x, i = blockIdx.y, j = threadIdx.x;
    if (j < NTOK)
        bias_full[(h * NTOK + i) * NTOK + j] = table[idx[i * NTOK + j] * 16 + h];
}

// ---------------- qkv GEMM: (100352x512 f32) @ (1536x512 f32)^T -> scattered bf16
__global__ __launch_bounds__(256)
void k_qkv(const float* __restrict__ x, const float* __restrict__ w,
           const float* __restrict__ qb, unsigned short* __restrict__ qkvbuf) {
    __shared__ short As[128][36];
    __shared__ short Bs[128][36];
    const int tid = threadIdx.x;
    const int m0 = blockIdx.x * 128, n0 = blockIdx.y * 128;
    const int wid = tid >> 6, l = tid & 63;
    const int wr = wid >> 1, wc = wid & 1;
    const int g = l >> 4, li = l & 15;
    const int srow = tid >> 1, scol = (tid & 1) * 16;

    f32x4 acc[4][4] = {};

    const float* ap = x + (size_t)(m0 + srow) * DIMC + scol;
    const float* bp = w + (size_t)(n0 + srow) * DIMC + scol;

    for (int k0 = 0; k0 < DIMC; k0 += 32) {
        float4 a0 = *(const float4*)(ap + k0);
        float4 a1 = *(const float4*)(ap + k0 + 4);
        float4 a2 = *(const float4*)(ap + k0 + 8);
        float4 a3 = *(const float4*)(ap + k0 + 12);
        float4 b0 = *(const float4*)(bp + k0);
        float4 b1 = *(const float4*)(bp + k0 + 4);
        float4 b2 = *(const float4*)(bp + k0 + 8);
        float4 b3 = *(const float4*)(bp + k0 + 12);
        *(bf16x8*)&As[srow][scol]     = cvt8(a0, a1);
        *(bf16x8*)&As[srow][scol + 8] = cvt8(a2, a3);
        *(bf16x8*)&Bs[srow][scol]     = cvt8(b0, b1);
        *(bf16x8*)&Bs[srow][scol + 8] = cvt8(b2, b3);
        __syncthreads();
        bf16x8 af[4], bfr[4];
        #pragma unroll
        for (int mm = 0; mm < 4; ++mm)
            af[mm] = *(bf16x8*)&As[wr * 64 + mm * 16 + li][g * 8];
        #pragma unroll
        for (int nn = 0; nn < 4; ++nn)
            bfr[nn] = *(bf16x8*)&Bs[wc * 64 + nn * 16 + li][g * 8];
        #pragma unroll
        for (int mm = 0; mm < 4; ++mm)
            #pragma unroll
            for (int nn = 0; nn < 4; ++nn)
                acc[mm][nn] = __builtin_amdgcn_mfma_f32_16x16x32_bf16(
                    af[mm], bfr[nn], acc[mm][nn], 0, 0, 0);
        __syncthreads();
    }

    #pragma unroll
    for (int mm = 0; mm < 4; ++mm) {
        #pragma unroll
        for (int nn = 0; nn < 4; ++nn) {
            int col = n0 + wc * 64 + nn * 16 + li;
            int which = col >> 9;
            int h = (col >> 5) & 15;
            int d = col & 31;
            float bv = qb[col];
            #pragma unroll
            for (int r = 0; r < 4; ++r) {
                int row = m0 + wr * 64 + mm * 16 + g * 4 + r;
                unsigned bw = (unsigned)row / 98u;
                unsigned nn_ = (unsigned)row - bw * 98u;
                float v = acc[mm][nn][r] + bv;
                if (which == 0) v *= 0.17677669529663689f;  // 1/sqrt(32)
                qkvbuf[(size_t)((bw * 16u + h) * 3u + which) * 3136u + nn_ * 32u + d] =
                    f2bf(v);
            }
        }
    }
}

// ---------------- attention: one block per (window b, head h) -------------------
__global__ __launch_bounds__(448)
void k_attn(unsigned short* __restrict__ qkvbuf, const float* __restrict__ mask,
            const float* __restrict__ bias_full) {
    __shared__ short Ks[112][36];
    __shared__ short Vt[32][132];
    __shared__ short Ps[7][16][132];

    const int tid = threadIdx.x;
    const int w = tid >> 6, l = tid & 63, g = l >> 4, li = l & 15;
    const int bh = blockIdx.x;
    const int b = bh >> 4, h = bh & 15;

    unsigned short* qslot = qkvbuf + (size_t)bh * 3 * 3136;
    const unsigned short* kslot = qslot + 3136;
    const unsigned short* vslot = qslot + 6272;

    if (tid < 392) {
        int row = tid >> 2, seg = (tid & 3) * 8;
        bf16x8 kv = *(const bf16x8*)(kslot + row * 32 + seg);
        *(bf16x8*)&Ks[row][seg] = kv;
        bf16x8 vv = *(const bf16x8*)(vslot + row * 32 + seg);
        #pragma unroll
        for (int j = 0; j < 8; ++j) Vt[seg + j][row] = vv[j];
    }
    // zero K rows 98..111 (cols 0..31): exactly 448 writes
    Ks[98 + (tid >> 5)][tid & 31] = 0;
    // zero Vt cols 98..131
    for (int t2 = tid; t2 < 32 * 34; t2 += 448) {
        int d = t2 / 34, c = t2 % 34;
        Vt[d][98 + c] = 0;
    }
    // zero P pad cols 112..131 (per-wave region)
    for (int t2 = l; t2 < 16 * 20; t2 += 64) {
        int r = t2 / 20, c = t2 % 20;
        Ps[w][r][112 + c] = 0;
    }

    // Q fragment straight from global (rows 16w..16w+15; rows>=98 are garbage, unused)
    bf16x8 aq = *(const bf16x8*)(qslot + (16 * w + li) * 32 + g * 8);

    __syncthreads();

    // S = (q*scale) @ K^T   (scale folded into Q at qkv epilogue)
    f32x4 s[7];
    #pragma unroll
    for (int j = 0; j < 7; ++j) {
        bf16x8 bk = *(bf16x8*)&Ks[16 * j + li][g * 8];
        f32x4 z = {};
        s[j] = __builtin_amdgcn_mfma_f32_16x16x32_bf16(aq, bk, z, 0, 0, 0);
    }

    const float* bp = bias_full + h * 9604;
    const float* mp = mask + (b & 63) * 9604;
    float sinv[4];
    #pragma unroll
    for (int r = 0; r < 4; ++r) {
        int i = 16 * w + g * 4 + r;
        bool rowok = (i < NTOK);
        float sv[7];
        float mx = -1e30f;
        #pragma unroll
        for (int j = 0; j < 7; ++j) {
            int col = 16 * j + li;
            float t = s[j][r];
            if (rowok && col < NTOK) t += bp[i * NTOK + col] + mp[i * NTOK + col];
            else t = -1e30f;
            sv[j] = t;
            mx = fmaxf(mx, t);
        }
        mx = fmaxf(mx, __shfl_xor(mx, 1));
        mx = fmaxf(mx, __shfl_xor(mx, 2));
        mx = fmaxf(mx, __shfl_xor(mx, 4));
        mx = fmaxf(mx, __shfl_xor(mx, 8));
        float sum = 0.f;
        #pragma unroll
        for (int j = 0; j < 7; ++j) {
            float p = __expf(sv[j] - mx);
            sum += p;
            Ps[w][g * 4 + r][16 * j + li] = (short)f2bf(p);
        }
        sum += __shfl_xor(sum, 1);
        sum += __shfl_xor(sum, 2);
        sum += __shfl_xor(sum, 4);
        sum += __shfl_xor(sum, 8);
        sinv[r] = 1.0f / sum;
    }

    __syncthreads();

    // O = P @ V  (K padded to 128 with zeros in both P and Vt)
    f32x4 o[2] = {};
    #pragma unroll
    for (int ks = 0; ks < 4; ++ks) {
        bf16x8 pa = *(bf16x8*)&Ps[w][li][ks * 32 + g * 8];
        #pragma unroll
        for (int ct = 0; ct < 2; ++ct) {
            bf16x8 vb = *(bf16x8*)&Vt[ct * 16 + li][ks * 32 + g * 8];
            o[ct] = __builtin_amdgcn_mfma_f32_16x16x32_bf16(pa, vb, o[ct], 0, 0, 0);
        }
    }

    // overwrite the (now dead) Q slot with O, normalized
    #pragma unroll
    for (int ct = 0; ct < 2; ++ct) {
        #pragma unroll
        for (int r = 0; r < 4; ++r) {
            int i = 16 * w + g * 4 + r;
            if (i < NTOK) {
                int d = ct * 16 + li;
                qslot[i * 32 + d] = f2bf(o[ct][r] * sinv[r]);
            }
        }
    }
}

// ---------------- proj GEMM: attn_out(bf16, strided in qkvbuf) @ proj_w^T + b ----
__global__ __launch_bounds__(256)
void k_proj(const unsigned short* __restrict__ qkvbuf, const float* __restrict__ w,
            const float* __restrict__ pb, float* __restrict__ out) {
    __shared__ short As[128][36];
    __shared__ short Bs[128][36];
    const int tid = threadIdx.x;
    const int m0 = blockIdx.x * 128, n0 = blockIdx.y * 128;
    const int wid = tid >> 6, l = tid & 63;
    const int wr = wid >> 1, wc = wid & 1;
    const int g = l >> 4, li = l & 15;
    const int srow = tid >> 1, scol = (tid & 1) * 16;

    unsigned row = m0 + srow;
    unsigned bw = row / 98u, nn_ = row - bw * 98u;
    const unsigned short* abase =
        qkvbuf + (size_t)bw * 48u * 3136u + (size_t)nn_ * 32u + scol;
    const float* bp = w + (size_t)(n0 + srow) * DIMC + scol;

    f32x4 acc[4][4] = {};

    for (int k0 = 0; k0 < DIMC; k0 += 32) {
        int hh = k0 >> 5;
        const unsigned short* ap = abase + (size_t)hh * 9408u;  // 3*3136
        bf16x8 A0 = *(const bf16x8*)ap;
        bf16x8 A1 = *(const bf16x8*)(ap + 8);
        float4 b0 = *(const float4*)(bp + k0);
        float4 b1 = *(const float4*)(bp + k0 + 4);
        float4 b2 = *(const float4*)(bp + k0 + 8);
        float4 b3 = *(const float4*)(bp + k0 + 12);
        *(bf16x8*)&As[srow][scol]     = A0;
        *(bf16x8*)&As[srow][scol + 8] = A1;
        *(bf16x8*)&Bs[srow][scol]     = cvt8(b0, b1);
        *(bf16x8*)&Bs[srow][scol + 8] = cvt8(b2, b3);
        __syncthreads();
        bf16x8 af[4], bfr[4];
        #pragma unroll
        for (int mm = 0; mm < 4; ++mm)
            af[mm] = *(bf16x8*)&As[wr * 64 + mm * 16 + li][g * 8];
        #pragma unroll
        for (int nn = 0; nn < 4; ++nn)
            bfr[nn] = *(bf16x8*)&Bs[wc * 64 + nn * 16 + li][g * 8];
        #pragma unroll
        for (int mm = 0; mm < 4; ++mm)
            #pragma unroll
            for (int nn = 0; nn < 4; ++nn)
                acc[mm][nn] = __builtin_amdgcn_mfma_f32_16x16x32_bf16(
                    af[mm], bfr[nn], acc[mm][nn], 0, 0, 0);
        __syncthreads();
    }

    #pragma unroll
    for (int mm = 0; mm < 4; ++mm) {
        #pragma unroll
        for (int nn = 0; nn < 4; ++nn) {
            int col = n0 + wc * 64 + nn * 16 + li;
            float bv = pb[col];
            #pragma unroll
            for (int r = 0; r < 4; ++r) {
                int row2 = m0 + wr * 64 + mm * 16 + g * 4 + r;
                out[(size_t)row2 * DIMC + col] = acc[mm][nn][r] + bv;
            }
        }
    }
}

extern "C" void kernel_launch(void* const* d_in, const int* in_sizes, int n_in,
                              void* d_out, int out_size, void* d_ws, size_t ws_size,
                              hipStream_t stream) {
    const float* x          = (const float*)d_in[0];
    const float* mask       = (const float*)d_in[1];
    const float* qkv_w      = (const float*)d_in[2];
    const float* qkv_b      = (const float*)d_in[3];
    const float* proj_w     = (const float*)d_in[4];
    const float* proj_b     = (const float*)d_in[5];
    const float* bias_table = (const float*)d_in[6];
    const int*   rel_idx    = (const int*)d_in[7];
    float* out = (float*)d_out;

    unsigned short* qkvbuf = (unsigned short*)d_ws;                 // 16384*3*3136 bf16
    float* bias_full = (float*)((char*)d_ws + (size_t)16384 * 3 * 3136 * 2);

    k_bias<<<dim3(16, 98), dim3(128), 0, stream>>>(bias_table, rel_idx, bias_full);
    k_qkv<<<dim3(784, 12), dim3(256), 0, stream>>>(x, qkv_w, qkv_b, qkvbuf);
    k_attn<<<dim3(16384), dim3(448), 0, stream>>>(qkvbuf, mask, bias_full);
    k_proj<<<dim3(784, 4), dim3(256), 0, stream>>>(qkvbuf, proj_w, proj_b, out);
}

// Round 2
// 767.155 us; speedup vs baseline: 1.2858x; 1.2858x over previous
//
#include <hip/hip_runtime.h>
#include <hip/hip_bf16.h>
#include <stdint.h>

#define DIMC 512
#define NTOK 98
// M_TOTAL = 1024*98 = 100352 = 784 * 128

typedef float f32x4 __attribute__((ext_vector_type(4)));
typedef short bf16x8 __attribute__((ext_vector_type(8)));

__device__ inline unsigned short f2bf(float f) {
    union { float f; uint32_t u; } v; v.f = f;
    uint32_t r = v.u + 0x7fffu + ((v.u >> 16) & 1u);
    return (unsigned short)(r >> 16);
}

__device__ inline bf16x8 cvt8(float4 a, float4 b) {
    bf16x8 r;
    r[0] = (short)f2bf(a.x); r[1] = (short)f2bf(a.y);
    r[2] = (short)f2bf(a.z); r[3] = (short)f2bf(a.w);
    r[4] = (short)f2bf(b.x); r[5] = (short)f2bf(b.y);
    r[6] = (short)f2bf(b.z); r[7] = (short)f2bf(b.w);
    return r;
}

__device__ __forceinline__ void gload16(const void* g, void* l) {
    __builtin_amdgcn_global_load_lds(
        (const __attribute__((address_space(1))) unsigned int*)g,
        (__attribute__((address_space(3))) unsigned int*)l, 16, 0, 0);
}

// ---------------- fp32 -> bf16 streaming convert (8 elems/thread) --------------
__global__ void k_cvt(const float* __restrict__ src, unsigned short* __restrict__ dst,
                      int n8) {
    int i = blockIdx.x * blockDim.x + threadIdx.x;
    if (i < n8) {
        float4 a = *(const float4*)(src + (size_t)i * 8);
        float4 b = *(const float4*)(src + (size_t)i * 8 + 4);
        *(bf16x8*)(dst + (size_t)i * 8) = cvt8(a, b);
    }
}

// ---------------- bias gather: bias_full[h][i][j] = table[idx[i][j]*16 + h] ----
__global__ void k_bias(const float* __restrict__ table, const int* __restrict__ idx,
                       float* __restrict__ bias_full) {
    int h = blockIdx.x, i = blockIdx.y, j = threadIdx.x;
    if (j < NTOK)
        bias_full[(h * NTOK + i) * NTOK + j] = table[idx[i * NTOK + j] * 16 + h];
}

// ================= m97-structure qkv GEMM (bf16 inputs, gload_lds staging) =====
__global__ __launch_bounds__(256)
void k_qkv2(const unsigned short* __restrict__ xb, const unsigned short* __restrict__ wb,
            const float* __restrict__ qb, unsigned short* __restrict__ qkvbuf) {
    __shared__ unsigned short As[128 * 32];
    __shared__ unsigned short Bs[128 * 32];
    const int tid = threadIdx.x;
    const int m0 = blockIdx.x * 128, n0 = blockIdx.y * 128;
    const int wid = tid >> 6, l = tid & 63;
    const int wr = wid >> 1, wc = wid & 1;
    const int g = l >> 4, li = l & 15;

    // staging: chunk c covers LDS bytes [c*16, c*16+16) = row c/4, cols (c%4)*8..+8
    const int r0 = tid >> 2, c0 = (tid & 3) * 8;
    const int r1 = (256 + tid) >> 2, c1 = (tid & 3) * 8;
    const unsigned short* a0p = xb + (size_t)(m0 + r0) * DIMC + c0;
    const unsigned short* a1p = xb + (size_t)(m0 + r1) * DIMC + c1;
    const unsigned short* b0p = wb + (size_t)(n0 + r0) * DIMC + c0;
    const unsigned short* b1p = wb + (size_t)(n0 + r1) * DIMC + c1;
    unsigned short* asl0 = As + (size_t)wid * 64 * 8;
    unsigned short* asl1 = As + 2048 + (size_t)wid * 64 * 8;
    unsigned short* bsl0 = Bs + (size_t)wid * 64 * 8;
    unsigned short* bsl1 = Bs + 2048 + (size_t)wid * 64 * 8;

    f32x4 acc[4][4] = {};

    for (int k0 = 0; k0 < DIMC; k0 += 32) {
        gload16(a0p + k0, asl0);
        gload16(a1p + k0, asl1);
        gload16(b0p + k0, bsl0);
        gload16(b1p + k0, bsl1);
        __syncthreads();
        bf16x8 af[4], bfr[4];
        #pragma unroll
        for (int mm = 0; mm < 4; ++mm)
            af[mm] = *(bf16x8*)&As[(wr * 64 + mm * 16 + li) * 32 + g * 8];
        #pragma unroll
        for (int nn = 0; nn < 4; ++nn)
            bfr[nn] = *(bf16x8*)&Bs[(wc * 64 + nn * 16 + li) * 32 + g * 8];
        #pragma unroll
        for (int mm = 0; mm < 4; ++mm)
            #pragma unroll
            for (int nn = 0; nn < 4; ++nn)
                acc[mm][nn] = __builtin_amdgcn_mfma_f32_16x16x32_bf16(
                    af[mm], bfr[nn], acc[mm][nn], 0, 0, 0);
        __syncthreads();
    }

    #pragma unroll
    for (int mm = 0; mm < 4; ++mm) {
        #pragma unroll
        for (int nn = 0; nn < 4; ++nn) {
            int col = n0 + wc * 64 + nn * 16 + li;
            int which = col >> 9;
            int h = (col >> 5) & 15;
            int d = col & 31;
            float bv = qb[col];
            #pragma unroll
            for (int r = 0; r < 4; ++r) {
                int row = m0 + wr * 64 + mm * 16 + g * 4 + r;
                unsigned bw = (unsigned)row / 98u;
                unsigned nn_ = (unsigned)row - bw * 98u;
                float v = acc[mm][nn][r] + bv;
                if (which == 0) v *= 0.17677669529663689f;  // 1/sqrt(32)
                qkvbuf[(size_t)((bw * 16u + h) * 3u + which) * 3136u + nn_ * 32u + d] =
                    f2bf(v);
            }
        }
    }
}

// ================= m97-structure proj GEMM (A gathered from qkvbuf) ============
__global__ __launch_bounds__(256)
void k_proj2(const unsigned short* __restrict__ qkvbuf,
             const unsigned short* __restrict__ wb,
             const float* __restrict__ pb, float* __restrict__ out) {
    __shared__ unsigned short As[128 * 32];
    __shared__ unsigned short Bs[128 * 32];
    const int tid = threadIdx.x;
    const int m0 = blockIdx.x * 128, n0 = blockIdx.y * 128;
    const int wid = tid >> 6, l = tid & 63;
    const int wr = wid >> 1, wc = wid & 1;
    const int g = l >> 4, li = l & 15;

    const int r0 = tid >> 2, c0 = (tid & 3) * 8;
    const int r1 = (256 + tid) >> 2, c1 = (tid & 3) * 8;
    // A rows live in qkvbuf at (bw*16 + h)*9408 + nn_*32 + d; h = k0/32 -> +9408/step
    unsigned row0 = m0 + r0, row1 = m0 + r1;
    unsigned bw0 = row0 / 98u, nn0 = row0 - bw0 * 98u;
    unsigned bw1 = row1 / 98u, nn1 = row1 - bw1 * 98u;
    const unsigned short* a0p = qkvbuf + (size_t)bw0 * 150528u + nn0 * 32u + c0;
    const unsigned short* a1p = qkvbuf + (size_t)bw1 * 150528u + nn1 * 32u + c1;
    const unsigned short* b0p = wb + (size_t)(n0 + r0) * DIMC + c0;
    const unsigned short* b1p = wb + (size_t)(n0 + r1) * DIMC + c1;
    unsigned short* asl0 = As + (size_t)wid * 64 * 8;
    unsigned short* asl1 = As + 2048 + (size_t)wid * 64 * 8;
    unsigned short* bsl0 = Bs + (size_t)wid * 64 * 8;
    unsigned short* bsl1 = Bs + 2048 + (size_t)wid * 64 * 8;

    f32x4 acc[4][4] = {};

    for (int k0 = 0; k0 < DIMC; k0 += 32) {
        size_t ao = (size_t)(k0 >> 5) * 9408u;
        gload16(a0p + ao, asl0);
        gload16(a1p + ao, asl1);
        gload16(b0p + k0, bsl0);
        gload16(b1p + k0, bsl1);
        __syncthreads();
        bf16x8 af[4], bfr[4];
        #pragma unroll
        for (int mm = 0; mm < 4; ++mm)
            af[mm] = *(bf16x8*)&As[(wr * 64 + mm * 16 + li) * 32 + g * 8];
        #pragma unroll
        for (int nn = 0; nn < 4; ++nn)
            bfr[nn] = *(bf16x8*)&Bs[(wc * 64 + nn * 16 + li) * 32 + g * 8];
        #pragma unroll
        for (int mm = 0; mm < 4; ++mm)
            #pragma unroll
            for (int nn = 0; nn < 4; ++nn)
                acc[mm][nn] = __builtin_amdgcn_mfma_f32_16x16x32_bf16(
                    af[mm], bfr[nn], acc[mm][nn], 0, 0, 0);
        __syncthreads();
    }

    #pragma unroll
    for (int mm = 0; mm < 4; ++mm) {
        #pragma unroll
        for (int nn = 0; nn < 4; ++nn) {
            int col = n0 + wc * 64 + nn * 16 + li;
            float bv = pb[col];
            #pragma unroll
            for (int r = 0; r < 4; ++r) {
                int row2 = m0 + wr * 64 + mm * 16 + g * 4 + r;
                out[(size_t)row2 * DIMC + col] = acc[mm][nn][r] + bv;
            }
        }
    }
}

// ---------------- attention: one block per (window b, head h) -------------------
__global__ __launch_bounds__(448)
void k_attn(unsigned short* __restrict__ qkvbuf, const float* __restrict__ mask,
            const float* __restrict__ bias_full) {
    __shared__ short Ks[112][36];
    __shared__ short Vt[32][132];
    __shared__ short Ps[7][16][132];

    const int tid = threadIdx.x;
    const int w = tid >> 6, l = tid & 63, g = l >> 4, li = l & 15;
    const int bh = blockIdx.x;
    const int b = bh >> 4, h = bh & 15;

    unsigned short* qslot = qkvbuf + (size_t)bh * 3 * 3136;
    const unsigned short* kslot = qslot + 3136;
    const unsigned short* vslot = qslot + 6272;

    if (tid < 392) {
        int row = tid >> 2, seg = (tid & 3) * 8;
        bf16x8 kv = *(const bf16x8*)(kslot + row * 32 + seg);
        *(bf16x8*)&Ks[row][seg] = kv;
        bf16x8 vv = *(const bf16x8*)(vslot + row * 32 + seg);
        #pragma unroll
        for (int j = 0; j < 8; ++j) Vt[seg + j][row] = vv[j];
    }
    Ks[98 + (tid >> 5)][tid & 31] = 0;
    for (int t2 = tid; t2 < 32 * 34; t2 += 448) {
        int d = t2 / 34, c = t2 % 34;
        Vt[d][98 + c] = 0;
    }
    for (int t2 = l; t2 < 16 * 20; t2 += 64) {
        int r = t2 / 20, c = t2 % 20;
        Ps[w][r][112 + c] = 0;
    }

    bf16x8 aq = *(const bf16x8*)(qslot + (16 * w + li) * 32 + g * 8);

    __syncthreads();

    f32x4 s[7];
    #pragma unroll
    for (int j = 0; j < 7; ++j) {
        bf16x8 bk = *(bf16x8*)&Ks[16 * j + li][g * 8];
        f32x4 z = {};
        s[j] = __builtin_amdgcn_mfma_f32_16x16x32_bf16(aq, bk, z, 0, 0, 0);
    }

    const float* bp = bias_full + h * 9604;
    const float* mp = mask + (b & 63) * 9604;
    float sinv[4];
    #pragma unroll
    for (int r = 0; r < 4; ++r) {
        int i = 16 * w + g * 4 + r;
        bool rowok = (i < NTOK);
        float sv[7];
        float mx = -1e30f;
        #pragma unroll
        for (int j = 0; j < 7; ++j) {
            int col = 16 * j + li;
            float t = s[j][r];
            if (rowok && col < NTOK) t += bp[i * NTOK + col] + mp[i * NTOK + col];
            else t = -1e30f;
            sv[j] = t;
            mx = fmaxf(mx, t);
        }
        mx = fmaxf(mx, __shfl_xor(mx, 1));
        mx = fmaxf(mx, __shfl_xor(mx, 2));
        mx = fmaxf(mx, __shfl_xor(mx, 4));
        mx = fmaxf(mx, __shfl_xor(mx, 8));
        float sum = 0.f;
        #pragma unroll
        for (int j = 0; j < 7; ++j) {
            float p = __expf(sv[j] - mx);
            sum += p;
            Ps[w][g * 4 + r][16 * j + li] = (short)f2bf(p);
        }
        sum += __shfl_xor(sum, 1);
        sum += __shfl_xor(sum, 2);
        sum += __shfl_xor(sum, 4);
        sum += __shfl_xor(sum, 8);
        sinv[r] = 1.0f / sum;
    }

    __syncthreads();

    f32x4 o[2] = {};
    #pragma unroll
    for (int ks = 0; ks < 4; ++ks) {
        bf16x8 pa = *(bf16x8*)&Ps[w][li][ks * 32 + g * 8];
        #pragma unroll
        for (int ct = 0; ct < 2; ++ct) {
            bf16x8 vb = *(bf16x8*)&Vt[ct * 16 + li][ks * 32 + g * 8];
            o[ct] = __builtin_amdgcn_mfma_f32_16x16x32_bf16(pa, vb, o[ct], 0, 0, 0);
        }
    }

    #pragma unroll
    for (int ct = 0; ct < 2; ++ct) {
        #pragma unroll
        for (int r = 0; r < 4; ++r) {
            int i = 16 * w + g * 4 + r;
            if (i < NTOK) {
                int d = ct * 16 + li;
                qslot[i * 32 + d] = f2bf(o[ct][r] * sinv[r]);
            }
        }
    }
}

// ================= fallback (round-1) fp32-staged GEMMs ========================
__global__ __launch_bounds__(256)
void k_qkv_old(const float* __restrict__ x, const float* __restrict__ w,
               const float* __restrict__ qb, unsigned short* __restrict__ qkvbuf) {
    __shared__ short As[128][36];
    __shared__ short Bs[128][36];
    const int tid = threadIdx.x;
    const int m0 = blockIdx.x * 128, n0 = blockIdx.y * 128;
    const int wid = tid >> 6, l = tid & 63;
    const int wr = wid >> 1, wc = wid & 1;
    const int g = l >> 4, li = l & 15;
    const int srow = tid >> 1, scol = (tid & 1) * 16;

    f32x4 acc[4][4] = {};
    const float* ap = x + (size_t)(m0 + srow) * DIMC + scol;
    const float* bp = w + (size_t)(n0 + srow) * DIMC + scol;

    for (int k0 = 0; k0 < DIMC; k0 += 32) {
        float4 a0 = *(const float4*)(ap + k0);
        float4 a1 = *(const float4*)(ap + k0 + 4);
        float4 a2 = *(const float4*)(ap + k0 + 8);
        float4 a3 = *(const float4*)(ap + k0 + 12);
        float4 b0 = *(const float4*)(bp + k0);
        float4 b1 = *(const float4*)(bp + k0 + 4);
        float4 b2 = *(const float4*)(bp + k0 + 8);
        float4 b3 = *(const float4*)(bp + k0 + 12);
        *(bf16x8*)&As[srow][scol]     = cvt8(a0, a1);
        *(bf16x8*)&As[srow][scol + 8] = cvt8(a2, a3);
        *(bf16x8*)&Bs[srow][scol]     = cvt8(b0, b1);
        *(bf16x8*)&Bs[srow][scol + 8] = cvt8(b2, b3);
        __syncthreads();
        bf16x8 af[4], bfr[4];
        #pragma unroll
        for (int mm = 0; mm < 4; ++mm)
            af[mm] = *(bf16x8*)&As[wr * 64 + mm * 16 + li][g * 8];
        #pragma unroll
        for (int nn = 0; nn < 4; ++nn)
            bfr[nn] = *(bf16x8*)&Bs[wc * 64 + nn * 16 + li][g * 8];
        #pragma unroll
        for (int mm = 0; mm < 4; ++mm)
            #pragma unroll
            for (int nn = 0; nn < 4; ++nn)
                acc[mm][nn] = __builtin_amdgcn_mfma_f32_16x16x32_bf16(
                    af[mm], bfr[nn], acc[mm][nn], 0, 0, 0);
        __syncthreads();
    }

    #pragma unroll
    for (int mm = 0; mm < 4; ++mm) {
        #pragma unroll
        for (int nn = 0; nn < 4; ++nn) {
            int col = n0 + wc * 64 + nn * 16 + li;
            int which = col >> 9;
            int h = (col >> 5) & 15;
            int d = col & 31;
            float bv = qb[col];
            #pragma unroll
            for (int r = 0; r < 4; ++r) {
                int row = m0 + wr * 64 + mm * 16 + g * 4 + r;
                unsigned bw = (unsigned)row / 98u;
                unsigned nn_ = (unsigned)row - bw * 98u;
                float v = acc[mm][nn][r] + bv;
                if (which == 0) v *= 0.17677669529663689f;
                qkvbuf[(size_t)((bw * 16u + h) * 3u + which) * 3136u + nn_ * 32u + d] =
                    f2bf(v);
            }
        }
    }
}

__global__ __launch_bounds__(256)
void k_proj_old(const unsigned short* __restrict__ qkvbuf, const float* __restrict__ w,
                const float* __restrict__ pb, float* __restrict__ out) {
    __shared__ short As[128][36];
    __shared__ short Bs[128][36];
    const int tid = threadIdx.x;
    const int m0 = blockIdx.x * 128, n0 = blockIdx.y * 128;
    const int wid = tid >> 6, l = tid & 63;
    const int wr = wid >> 1, wc = wid & 1;
    const int g = l >> 4, li = l & 15;
    const int srow = tid >> 1, scol = (tid & 1) * 16;

    unsigned row = m0 + srow;
    unsigned bw = row / 98u, nn_ = row - bw * 98u;
    const unsigned short* abase =
        qkvbuf + (size_t)bw * 48u * 3136u + (size_t)nn_ * 32u + scol;
    const float* bp = w + (size_t)(n0 + srow) * DIMC + scol;

    f32x4 acc[4][4] = {};

    for (int k0 = 0; k0 < DIMC; k0 += 32) {
        int hh = k0 >> 5;
        const unsigned short* ap = abase + (size_t)hh * 9408u;
        bf16x8 A0 = *(const bf16x8*)ap;
        bf16x8 A1 = *(const bf16x8*)(ap + 8);
        float4 b0 = *(const float4*)(bp + k0);
        float4 b1 = *(const float4*)(bp + k0 + 4);
        float4 b2 = *(const float4*)(bp + k0 + 8);
        float4 b3 = *(const float4*)(bp + k0 + 12);
        *(bf16x8*)&As[srow][scol]     = A0;
        *(bf16x8*)&As[srow][scol + 8] = A1;
        *(bf16x8*)&Bs[srow][scol]     = cvt8(b0, b1);
        *(bf16x8*)&Bs[srow][scol + 8] = cvt8(b2, b3);
        __syncthreads();
        bf16x8 af[4], bfr[4];
        #pragma unroll
        for (int mm = 0; mm < 4; ++mm)
            af[mm] = *(bf16x8*)&As[wr * 64 + mm * 16 + li][g * 8];
        #pragma unroll
        for (int nn = 0; nn < 4; ++nn)
            bfr[nn] = *(bf16x8*)&Bs[wc * 64 + nn * 16 + li][g * 8];
        #pragma unroll
        for (int mm = 0; mm < 4; ++mm)
            #pragma unroll
            for (int nn = 0; nn < 4; ++nn)
                acc[mm][nn] = __builtin_amdgcn_mfma_f32_16x16x32_bf16(
                    af[mm], bfr[nn], acc[mm][nn], 0, 0, 0);
        __syncthreads();
    }

    #pragma unroll
    for (int mm = 0; mm < 4; ++mm) {
        #pragma unroll
        for (int nn = 0; nn < 4; ++nn) {
            int col = n0 + wc * 64 + nn * 16 + li;
            float bv = pb[col];
            #pragma unroll
            for (int r = 0; r < 4; ++r) {
                int row2 = m0 + wr * 64 + mm * 16 + g * 4 + r;
                out[(size_t)row2 * DIMC + col] = acc[mm][nn][r] + bv;
            }
        }
    }
}

extern "C" void kernel_launch(void* const* d_in, const int* in_sizes, int n_in,
                              void* d_out, int out_size, void* d_ws, size_t ws_size,
                              hipStream_t stream) {
    const float* x          = (const float*)d_in[0];
    const float* mask       = (const float*)d_in[1];
    const float* qkv_w      = (const float*)d_in[2];
    const float* qkv_b      = (const float*)d_in[3];
    const float* proj_w     = (const float*)d_in[4];
    const float* proj_b     = (const float*)d_in[5];
    const float* bias_table = (const float*)d_in[6];
    const int*   rel_idx    = (const int*)d_in[7];
    float* out = (float*)d_out;

    // workspace layout (bytes)
    const size_t QKV_BYTES  = (size_t)16384 * 3 * 3136 * 2;      // 308,281,344
    const size_t BIAS_BYTES = (size_t)16 * 98 * 98 * 4;          // 614,656
    const size_t XB_BYTES   = (size_t)100352 * 512 * 2;          // 102,760,448
    const size_t WQ_BYTES   = (size_t)1536 * 512 * 2;            // 1,572,864
    const size_t WP_BYTES   = (size_t)512 * 512 * 2;             // 524,288

    unsigned short* qkvbuf = (unsigned short*)d_ws;
    float* bias_full = (float*)((char*)d_ws + QKV_BYTES);

    const size_t need = QKV_BYTES + BIAS_BYTES + XB_BYTES + WQ_BYTES + WP_BYTES;

    k_bias<<<dim3(16, 98), dim3(128), 0, stream>>>(bias_table, rel_idx, bias_full);

    if (ws_size >= need) {
        unsigned short* xb = (unsigned short*)((char*)d_ws + QKV_BYTES + BIAS_BYTES);
        unsigned short* wqb = xb + (size_t)100352 * 512;
        unsigned short* wpb = wqb + (size_t)1536 * 512;

        k_cvt<<<dim3(25088), dim3(256), 0, stream>>>(x, xb, 6422528);
        k_cvt<<<dim3(384),   dim3(256), 0, stream>>>(qkv_w, wqb, 98304);
        k_cvt<<<dim3(128),   dim3(256), 0, stream>>>(proj_w, wpb, 32768);

        k_qkv2<<<dim3(784, 12), dim3(256), 0, stream>>>(xb, wqb, qkv_b, qkvbuf);
        k_attn<<<dim3(16384), dim3(448), 0, stream>>>(qkvbuf, mask, bias_full);
        k_proj2<<<dim3(784, 4), dim3(256), 0, stream>>>(qkvbuf, wpb, proj_b, out);
    } else {
        k_qkv_old<<<dim3(784, 12), dim3(256), 0, stream>>>(x, qkv_w, qkv_b, qkvbuf);
        k_attn<<<dim3(16384), dim3(448), 0, stream>>>(qkvbuf, mask, bias_full);
        k_proj_old<<<dim3(784, 4), dim3(256), 0, stream>>>(qkvbuf, proj_w, proj_b, out);
    }
}

// Round 3
// 734.657 us; speedup vs baseline: 1.3427x; 1.0442x over previous
//
#include <hip/hip_runtime.h>
#include <hip/hip_bf16.h>
#include <stdint.h>

#define DIMC 512
#define NTOK 98
// M_TOTAL = 1024*98 = 100352 = 784 * 128

typedef float f32x4 __attribute__((ext_vector_type(4)));
typedef short bf16x8 __attribute__((ext_vector_type(8)));

__device__ inline unsigned short f2bf(float f) {
    union { float f; uint32_t u; } v; v.f = f;
    uint32_t r = v.u + 0x7fffu + ((v.u >> 16) & 1u);
    return (unsigned short)(r >> 16);
}

__device__ inline bf16x8 cvt8(float4 a, float4 b) {
    bf16x8 r;
    r[0] = (short)f2bf(a.x); r[1] = (short)f2bf(a.y);
    r[2] = (short)f2bf(a.z); r[3] = (short)f2bf(a.w);
    r[4] = (short)f2bf(b.x); r[5] = (short)f2bf(b.y);
    r[6] = (short)f2bf(b.z); r[7] = (short)f2bf(b.w);
    return r;
}

__device__ __forceinline__ void gload16(const void* g, void* l) {
    __builtin_amdgcn_global_load_lds(
        (const __attribute__((address_space(1))) unsigned int*)g,
        (__attribute__((address_space(3))) unsigned int*)l, 16, 0, 0);
}

// ---------------- fp32 -> bf16 streaming convert (8 elems/thread) --------------
__global__ void k_cvt(const float* __restrict__ src, unsigned short* __restrict__ dst,
                      int n8) {
    int i = blockIdx.x * blockDim.x + threadIdx.x;
    if (i < n8) {
        float4 a = *(const float4*)(src + (size_t)i * 8);
        float4 b = *(const float4*)(src + (size_t)i * 8 + 4);
        *(bf16x8*)(dst + (size_t)i * 8) = cvt8(a, b);
    }
}

// ---------------- combined bias+mask table, transposed + log2e-scaled ----------
// bm_t[slice][c (112)][i (100)] = (table[idx[i][c]*16+h] + mask[b64][i][c]) * log2e
// pads (c>=98 or i>=98) = -1e9 -> exp2 -> 0 (replaces masking branches in attn)
__global__ void k_bm(const float* __restrict__ table, const int* __restrict__ idx,
                     const float* __restrict__ mask, float* __restrict__ bm_t) {
    int slice = blockIdx.x;            // 0..1023 = b64*16 + h
    int b64 = slice >> 4, h = slice & 15;
    float* dst = bm_t + (size_t)slice * 11200;   // 112*100
    const float* mp = mask + (size_t)b64 * 9604;
    for (int t = threadIdx.x; t < 11200; t += blockDim.x) {
        int c = t / 100, i = t - c * 100;
        float v = -1e9f;
        if (c < NTOK && i < NTOK)
            v = (table[idx[i * NTOK + c] * 16 + h] + mp[i * NTOK + c])
                * 1.4426950408889634f;
        dst[t] = v;
    }
}

// ================= m97-structure qkv GEMM (bf16 in, gload_lds, XCD swizzle) ====
__global__ __launch_bounds__(256)
void k_qkv2(const unsigned short* __restrict__ xb, const unsigned short* __restrict__ wb,
            const float* __restrict__ qb, unsigned short* __restrict__ qkvbuf) {
    __shared__ unsigned short As[128 * 32];
    __shared__ unsigned short Bs[128 * 32];
    const int tid = threadIdx.x;
    // XCD-aware remap: id%8 = XCD; each XCD owns 98 contiguous m-tiles,
    // the 12 n-tiles of one m-panel run back-to-back -> A-panel L2-resident.
    const int id = blockIdx.x;
    const int xcd = id & 7, local = id >> 3;
    const int mt = xcd * 98 + local / 12;
    const int nt = local - (local / 12) * 12;
    const int m0 = mt * 128, n0 = nt * 128;
    const int wid = tid >> 6, l = tid & 63;
    const int wr = wid >> 1, wc = wid & 1;
    const int g = l >> 4, li = l & 15;

    const int r0 = tid >> 2, c0 = (tid & 3) * 8;
    const int r1 = (256 + tid) >> 2, c1 = (tid & 3) * 8;
    const unsigned short* a0p = xb + (size_t)(m0 + r0) * DIMC + c0;
    const unsigned short* a1p = xb + (size_t)(m0 + r1) * DIMC + c1;
    const unsigned short* b0p = wb + (size_t)(n0 + r0) * DIMC + c0;
    const unsigned short* b1p = wb + (size_t)(n0 + r1) * DIMC + c1;
    unsigned short* asl0 = As + (size_t)wid * 64 * 8;
    unsigned short* asl1 = As + 2048 + (size_t)wid * 64 * 8;
    unsigned short* bsl0 = Bs + (size_t)wid * 64 * 8;
    unsigned short* bsl1 = Bs + 2048 + (size_t)wid * 64 * 8;

    f32x4 acc[4][4] = {};

    for (int k0 = 0; k0 < DIMC; k0 += 32) {
        gload16(a0p + k0, asl0);
        gload16(a1p + k0, asl1);
        gload16(b0p + k0, bsl0);
        gload16(b1p + k0, bsl1);
        __syncthreads();
        bf16x8 af[4], bfr[4];
        #pragma unroll
        for (int mm = 0; mm < 4; ++mm)
            af[mm] = *(bf16x8*)&As[(wr * 64 + mm * 16 + li) * 32 + g * 8];
        #pragma unroll
        for (int nn = 0; nn < 4; ++nn)
            bfr[nn] = *(bf16x8*)&Bs[(wc * 64 + nn * 16 + li) * 32 + g * 8];
        #pragma unroll
        for (int mm = 0; mm < 4; ++mm)
            #pragma unroll
            for (int nn = 0; nn < 4; ++nn)
                acc[mm][nn] = __builtin_amdgcn_mfma_f32_16x16x32_bf16(
                    af[mm], bfr[nn], acc[mm][nn], 0, 0, 0);
        __syncthreads();
    }

    #pragma unroll
    for (int mm = 0; mm < 4; ++mm) {
        #pragma unroll
        for (int nn = 0; nn < 4; ++nn) {
            int col = n0 + wc * 64 + nn * 16 + li;
            int which = col >> 9;
            int h = (col >> 5) & 15;
            int d = col & 31;
            float bv = qb[col];
            #pragma unroll
            for (int r = 0; r < 4; ++r) {
                int row = m0 + wr * 64 + mm * 16 + g * 4 + r;
                unsigned bw = (unsigned)row / 98u;
                unsigned nn_ = (unsigned)row - bw * 98u;
                float v = acc[mm][nn][r] + bv;
                // fold softmax scale AND log2e into q
                if (which == 0) v *= 0.17677669529663689f * 1.4426950408889634f;
                qkvbuf[(size_t)((bw * 16u + h) * 3u + which) * 3136u + nn_ * 32u + d] =
                    f2bf(v);
            }
        }
    }
}

// ================= proj GEMM (A gathered from qkvbuf, XCD swizzle) =============
__global__ __launch_bounds__(256)
void k_proj2(const unsigned short* __restrict__ qkvbuf,
             const unsigned short* __restrict__ wb,
             const float* __restrict__ pb, float* __restrict__ out) {
    __shared__ unsigned short As[128 * 32];
    __shared__ unsigned short Bs[128 * 32];
    const int tid = threadIdx.x;
    const int id = blockIdx.x;
    const int xcd = id & 7, local = id >> 3;
    const int mt = xcd * 98 + local / 4;
    const int nt = local & 3;
    const int m0 = mt * 128, n0 = nt * 128;
    const int wid = tid >> 6, l = tid & 63;
    const int wr = wid >> 1, wc = wid & 1;
    const int g = l >> 4, li = l & 15;

    const int r0 = tid >> 2, c0 = (tid & 3) * 8;
    const int r1 = (256 + tid) >> 2, c1 = (tid & 3) * 8;
    unsigned row0 = m0 + r0, row1 = m0 + r1;
    unsigned bw0 = row0 / 98u, nn0 = row0 - bw0 * 98u;
    unsigned bw1 = row1 / 98u, nn1 = row1 - bw1 * 98u;
    const unsigned short* a0p = qkvbuf + (size_t)bw0 * 150528u + nn0 * 32u + c0;
    const unsigned short* a1p = qkvbuf + (size_t)bw1 * 150528u + nn1 * 32u + c1;
    const unsigned short* b0p = wb + (size_t)(n0 + r0) * DIMC + c0;
    const unsigned short* b1p = wb + (size_t)(n0 + r1) * DIMC + c1;
    unsigned short* asl0 = As + (size_t)wid * 64 * 8;
    unsigned short* asl1 = As + 2048 + (size_t)wid * 64 * 8;
    unsigned short* bsl0 = Bs + (size_t)wid * 64 * 8;
    unsigned short* bsl1 = Bs + 2048 + (size_t)wid * 64 * 8;

    f32x4 acc[4][4] = {};

    for (int k0 = 0; k0 < DIMC; k0 += 32) {
        size_t ao = (size_t)(k0 >> 5) * 9408u;
        gload16(a0p + ao, asl0);
        gload16(a1p + ao, asl1);
        gload16(b0p + k0, bsl0);
        gload16(b1p + k0, bsl1);
        __syncthreads();
        bf16x8 af[4], bfr[4];
        #pragma unroll
        for (int mm = 0; mm < 4; ++mm)
            af[mm] = *(bf16x8*)&As[(wr * 64 + mm * 16 + li) * 32 + g * 8];
        #pragma unroll
        for (int nn = 0; nn < 4; ++nn)
            bfr[nn] = *(bf16x8*)&Bs[(wc * 64 + nn * 16 + li) * 32 + g * 8];
        #pragma unroll
        for (int mm = 0; mm < 4; ++mm)
            #pragma unroll
            for (int nn = 0; nn < 4; ++nn)
                acc[mm][nn] = __builtin_amdgcn_mfma_f32_16x16x32_bf16(
                    af[mm], bfr[nn], acc[mm][nn], 0, 0, 0);
        __syncthreads();
    }

    #pragma unroll
    for (int mm = 0; mm < 4; ++mm) {
        #pragma unroll
        for (int nn = 0; nn < 4; ++nn) {
            int col = n0 + wc * 64 + nn * 16 + li;
            float bv = pb[col];
            #pragma unroll
            for (int r = 0; r < 4; ++r) {
                int row2 = m0 + wr * 64 + mm * 16 + g * 4 + r;
                out[(size_t)row2 * DIMC + col] = acc[mm][nn][r] + bv;
            }
        }
    }
}

// ---------------- attention: one block per (window b, head h) -------------------
__global__ __launch_bounds__(448)
void k_attn(unsigned short* __restrict__ qkvbuf, const float* __restrict__ bm_t) {
    __shared__ short Ks[112][36];
    __shared__ short Vt[32][132];
    __shared__ short Ps[7][16][132];

    const int tid = threadIdx.x;
    const int w = tid >> 6, l = tid & 63, g = l >> 4, li = l & 15;
    const int bh = blockIdx.x;
    const int slice = bh & 1023;      // (b%64)*16 + h

    unsigned short* qslot = qkvbuf + (size_t)bh * 3 * 3136;
    const unsigned short* kslot = qslot + 3136;
    const unsigned short* vslot = qslot + 6272;

    // ---- issue all global loads up front (latency hides under staging) ----
    // bias+mask fragments: MFMA C-operand, rows i0..i0+3 of col c = 16j+li
    const float* bmp = bm_t + (size_t)slice * 11200 + (16 * w + g * 4);
    f32x4 bmf[7];
    #pragma unroll
    for (int j = 0; j < 7; ++j)
        bmf[j] = *(const f32x4*)(bmp + (16 * j + li) * 100);

    bf16x8 aq = *(const bf16x8*)(qslot + (16 * w + li) * 32 + g * 8);

    if (tid < 392) {
        int row = tid >> 2, seg = (tid & 3) * 8;
        bf16x8 kv = *(const bf16x8*)(kslot + row * 32 + seg);
        *(bf16x8*)&Ks[row][seg] = kv;
        bf16x8 vv = *(const bf16x8*)(vslot + row * 32 + seg);
        #pragma unroll
        for (int j = 0; j < 8; ++j) Vt[seg + j][row] = vv[j];
    }
    Ks[98 + (tid >> 5)][tid & 31] = 0;
    for (int t2 = tid; t2 < 32 * 34; t2 += 448) {
        int d = t2 / 34, c = t2 % 34;
        Vt[d][98 + c] = 0;
    }
    for (int t2 = l; t2 < 16 * 20; t2 += 64) {
        int r = t2 / 20, c = t2 % 20;
        Ps[w][r][112 + c] = 0;
    }

    __syncthreads();

    // S = q@K^T + bias + mask  (bias/mask as C-operand; scale+log2e folded in q)
    f32x4 s[7];
    __builtin_amdgcn_s_setprio(1);
    #pragma unroll
    for (int j = 0; j < 7; ++j) {
        bf16x8 bk = *(bf16x8*)&Ks[16 * j + li][g * 8];
        s[j] = __builtin_amdgcn_mfma_f32_16x16x32_bf16(aq, bk, bmf[j], 0, 0, 0);
    }
    __builtin_amdgcn_s_setprio(0);

    // softmax: pads carry -1e9 bias -> exp2 -> 0, no masking branches
    float sinv[4];
    #pragma unroll
    for (int r = 0; r < 4; ++r) {
        float mx = s[0][r];
        #pragma unroll
        for (int j = 1; j < 7; ++j) mx = fmaxf(mx, s[j][r]);
        mx = fmaxf(mx, __shfl_xor(mx, 1));
        mx = fmaxf(mx, __shfl_xor(mx, 2));
        mx = fmaxf(mx, __shfl_xor(mx, 4));
        mx = fmaxf(mx, __shfl_xor(mx, 8));
        float sum = 0.f;
        #pragma unroll
        for (int j = 0; j < 7; ++j) {
            float p = exp2f(s[j][r] - mx);
            sum += p;
            Ps[w][g * 4 + r][16 * j + li] = (short)f2bf(p);
        }
        sum += __shfl_xor(sum, 1);
        sum += __shfl_xor(sum, 2);
        sum += __shfl_xor(sum, 4);
        sum += __shfl_xor(sum, 8);
        sinv[r] = 1.0f / sum;
    }

    __syncthreads();

    f32x4 o[2] = {};
    __builtin_amdgcn_s_setprio(1);
    #pragma unroll
    for (int ks = 0; ks < 4; ++ks) {
        bf16x8 pa = *(bf16x8*)&Ps[w][li][ks * 32 + g * 8];
        #pragma unroll
        for (int ct = 0; ct < 2; ++ct) {
            bf16x8 vb = *(bf16x8*)&Vt[ct * 16 + li][ks * 32 + g * 8];
            o[ct] = __builtin_amdgcn_mfma_f32_16x16x32_bf16(pa, vb, o[ct], 0, 0, 0);
        }
    }
    __builtin_amdgcn_s_setprio(0);

    #pragma unroll
    for (int ct = 0; ct < 2; ++ct) {
        #pragma unroll
        for (int r = 0; r < 4; ++r) {
            int i = 16 * w + g * 4 + r;
            if (i < NTOK) {
                int d = ct * 16 + li;
                qslot[i * 32 + d] = f2bf(o[ct][r] * sinv[r]);
            }
        }
    }
}

// ================= fallback (round-1) path =====================================
__global__ void k_bias(const float* __restrict__ table, const int* __restrict__ idx,
                       float* __restrict__ bias_full) {
    int h = blockIdx.x, i = blockIdx.y, j = threadIdx.x;
    if (j < NTOK)
        bias_full[(h * NTOK + i) * NTOK + j] = table[idx[i * NTOK + j] * 16 + h];
}

__global__ __launch_bounds__(256)
void k_qkv_old(const float* __restrict__ x, const float* __restrict__ w,
               const float* __restrict__ qb, unsigned short* __restrict__ qkvbuf) {
    __shared__ short As[128][36];
    __shared__ short Bs[128][36];
    const int tid = threadIdx.x;
    const int m0 = blockIdx.x * 128, n0 = blockIdx.y * 128;
    const int wid = tid >> 6, l = tid & 63;
    const int wr = wid >> 1, wc = wid & 1;
    const int g = l >> 4, li = l & 15;
    const int srow = tid >> 1, scol = (tid & 1) * 16;

    f32x4 acc[4][4] = {};
    const float* ap = x + (size_t)(m0 + srow) * DIMC + scol;
    const float* bp = w + (size_t)(n0 + srow) * DIMC + scol;

    for (int k0 = 0; k0 < DIMC; k0 += 32) {
        float4 a0 = *(const float4*)(ap + k0);
        float4 a1 = *(const float4*)(ap + k0 + 4);
        float4 a2 = *(const float4*)(ap + k0 + 8);
        float4 a3 = *(const float4*)(ap + k0 + 12);
        float4 b0 = *(const float4*)(bp + k0);
        float4 b1 = *(const float4*)(bp + k0 + 4);
        float4 b2 = *(const float4*)(bp + k0 + 8);
        float4 b3 = *(const float4*)(bp + k0 + 12);
        *(bf16x8*)&As[srow][scol]     = cvt8(a0, a1);
        *(bf16x8*)&As[srow][scol + 8] = cvt8(a2, a3);
        *(bf16x8*)&Bs[srow][scol]     = cvt8(b0, b1);
        *(bf16x8*)&Bs[srow][scol + 8] = cvt8(b2, b3);
        __syncthreads();
        bf16x8 af[4], bfr[4];
        #pragma unroll
        for (int mm = 0; mm < 4; ++mm)
            af[mm] = *(bf16x8*)&As[wr * 64 + mm * 16 + li][g * 8];
        #pragma unroll
        for (int nn = 0; nn < 4; ++nn)
            bfr[nn] = *(bf16x8*)&Bs[wc * 64 + nn * 16 + li][g * 8];
        #pragma unroll
        for (int mm = 0; mm < 4; ++mm)
            #pragma unroll
            for (int nn = 0; nn < 4; ++nn)
                acc[mm][nn] = __builtin_amdgcn_mfma_f32_16x16x32_bf16(
                    af[mm], bfr[nn], acc[mm][nn], 0, 0, 0);
        __syncthreads();
    }

    #pragma unroll
    for (int mm = 0; mm < 4; ++mm) {
        #pragma unroll
        for (int nn = 0; nn < 4; ++nn) {
            int col = n0 + wc * 64 + nn * 16 + li;
            int which = col >> 9;
            int h = (col >> 5) & 15;
            int d = col & 31;
            float bv = qb[col];
            #pragma unroll
            for (int r = 0; r < 4; ++r) {
                int row = m0 + wr * 64 + mm * 16 + g * 4 + r;
                unsigned bw = (unsigned)row / 98u;
                unsigned nn_ = (unsigned)row - bw * 98u;
                float v = acc[mm][nn][r] + bv;
                if (which == 0) v *= 0.17677669529663689f;
                qkvbuf[(size_t)((bw * 16u + h) * 3u + which) * 3136u + nn_ * 32u + d] =
                    f2bf(v);
            }
        }
    }
}

__global__ __launch_bounds__(448)
void k_attn_old(unsigned short* __restrict__ qkvbuf, const float* __restrict__ mask,
                const float* __restrict__ bias_full) {
    __shared__ short Ks[112][36];
    __shared__ short Vt[32][132];
    __shared__ short Ps[7][16][132];

    const int tid = threadIdx.x;
    const int w = tid >> 6, l = tid & 63, g = l >> 4, li = l & 15;
    const int bh = blockIdx.x;
    const int b = bh >> 4, h = bh & 15;

    unsigned short* qslot = qkvbuf + (size_t)bh * 3 * 3136;
    const unsigned short* kslot = qslot + 3136;
    const unsigned short* vslot = qslot + 6272;

    if (tid < 392) {
        int row = tid >> 2, seg = (tid & 3) * 8;
        bf16x8 kv = *(const bf16x8*)(kslot + row * 32 + seg);
        *(bf16x8*)&Ks[row][seg] = kv;
        bf16x8 vv = *(const bf16x8*)(vslot + row * 32 + seg);
        #pragma unroll
        for (int j = 0; j < 8; ++j) Vt[seg + j][row] = vv[j];
    }
    Ks[98 + (tid >> 5)][tid & 31] = 0;
    for (int t2 = tid; t2 < 32 * 34; t2 += 448) {
        int d = t2 / 34, c = t2 % 34;
        Vt[d][98 + c] = 0;
    }
    for (int t2 = l; t2 < 16 * 20; t2 += 64) {
        int r = t2 / 20, c = t2 % 20;
        Ps[w][r][112 + c] = 0;
    }

    bf16x8 aq = *(const bf16x8*)(qslot + (16 * w + li) * 32 + g * 8);

    __syncthreads();

    f32x4 s[7];
    #pragma unroll
    for (int j = 0; j < 7; ++j) {
        bf16x8 bk = *(bf16x8*)&Ks[16 * j + li][g * 8];
        f32x4 z = {};
        s[j] = __builtin_amdgcn_mfma_f32_16x16x32_bf16(aq, bk, z, 0, 0, 0);
    }

    const float* bp = bias_full + h * 9604;
    const float* mp = mask + (b & 63) * 9604;
    float sinv[4];
    #pragma unroll
    for (int r = 0; r < 4; ++r) {
        int i = 16 * w + g * 4 + r;
        bool rowok = (i < NTOK);
        float sv[7];
        float mx = -1e30f;
        #pragma unroll
        for (int j = 0; j < 7; ++j) {
            int col = 16 * j + li;
            float t = s[j][r];
            if (rowok && col < NTOK) t += bp[i * NTOK + col] + mp[i * NTOK + col];
            else t = -1e30f;
            sv[j] = t;
            mx = fmaxf(mx, t);
        }
        mx = fmaxf(mx, __shfl_xor(mx, 1));
        mx = fmaxf(mx, __shfl_xor(mx, 2));
        mx = fmaxf(mx, __shfl_xor(mx, 4));
        mx = fmaxf(mx, __shfl_xor(mx, 8));
        float sum = 0.f;
        #pragma unroll
        for (int j = 0; j < 7; ++j) {
            float p = __expf(sv[j] - mx);
            sum += p;
            Ps[w][g * 4 + r][16 * j + li] = (short)f2bf(p);
        }
        sum += __shfl_xor(sum, 1);
        sum += __shfl_xor(sum, 2);
        sum += __shfl_xor(sum, 4);
        sum += __shfl_xor(sum, 8);
        sinv[r] = 1.0f / sum;
    }

    __syncthreads();

    f32x4 o[2] = {};
    #pragma unroll
    for (int ks = 0; ks < 4; ++ks) {
        bf16x8 pa = *(bf16x8*)&Ps[w][li][ks * 32 + g * 8];
        #pragma unroll
        for (int ct = 0; ct < 2; ++ct) {
            bf16x8 vb = *(bf16x8*)&Vt[ct * 16 + li][ks * 32 + g * 8];
            o[ct] = __builtin_amdgcn_mfma_f32_16x16x32_bf16(pa, vb, o[ct], 0, 0, 0);
        }
    }

    #pragma unroll
    for (int ct = 0; ct < 2; ++ct) {
        #pragma unroll
        for (int r = 0; r < 4; ++r) {
            int i = 16 * w + g * 4 + r;
            if (i < NTOK) {
                int d = ct * 16 + li;
                qslot[i * 32 + d] = f2bf(o[ct][r] * sinv[r]);
            }
        }
    }
}

__global__ __launch_bounds__(256)
void k_proj_old(const unsigned short* __restrict__ qkvbuf, const float* __restrict__ w,
                const float* __restrict__ pb, float* __restrict__ out) {
    __shared__ short As[128][36];
    __shared__ short Bs[128][36];
    const int tid = threadIdx.x;
    const int m0 = blockIdx.x * 128, n0 = blockIdx.y * 128;
    const int wid = tid >> 6, l = tid & 63;
    const int wr = wid >> 1, wc = wid & 1;
    const int g = l >> 4, li = l & 15;
    const int srow = tid >> 1, scol = (tid & 1) * 16;

    unsigned row = m0 + srow;
    unsigned bw = row / 98u, nn_ = row - bw * 98u;
    const unsigned short* abase =
        qkvbuf + (size_t)bw * 48u * 3136u + (size_t)nn_ * 32u + scol;
    const float* bp = w + (size_t)(n0 + srow) * DIMC + scol;

    f32x4 acc[4][4] = {};

    for (int k0 = 0; k0 < DIMC; k0 += 32) {
        int hh = k0 >> 5;
        const unsigned short* ap = abase + (size_t)hh * 9408u;
        bf16x8 A0 = *(const bf16x8*)ap;
        bf16x8 A1 = *(const bf16x8*)(ap + 8);
        float4 b0 = *(const float4*)(bp + k0);
        float4 b1 = *(const float4*)(bp + k0 + 4);
        float4 b2 = *(const float4*)(bp + k0 + 8);
        float4 b3 = *(const float4*)(bp + k0 + 12);
        *(bf16x8*)&As[srow][scol]     = A0;
        *(bf16x8*)&As[srow][scol + 8] = A1;
        *(bf16x8*)&Bs[srow][scol]     = cvt8(b0, b1);
        *(bf16x8*)&Bs[srow][scol + 8] = cvt8(b2, b3);
        __syncthreads();
        bf16x8 af[4], bfr[4];
        #pragma unroll
        for (int mm = 0; mm < 4; ++mm)
            af[mm] = *(bf16x8*)&As[wr * 64 + mm * 16 + li][g * 8];
        #pragma unroll
        for (int nn = 0; nn < 4; ++nn)
            bfr[nn] = *(bf16x8*)&Bs[wc * 64 + nn * 16 + li][g * 8];
        #pragma unroll
        for (int mm = 0; mm < 4; ++mm)
            #pragma unroll
            for (int nn = 0; nn < 4; ++nn)
                acc[mm][nn] = __builtin_amdgcn_mfma_f32_16x16x32_bf16(
                    af[mm], bfr[nn], acc[mm][nn], 0, 0, 0);
        __syncthreads();
    }

    #pragma unroll
    for (int mm = 0; mm < 4; ++mm) {
        #pragma unroll
        for (int nn = 0; nn < 4; ++nn) {
            int col = n0 + wc * 64 + nn * 16 + li;
            float bv = pb[col];
            #pragma unroll
            for (int r = 0; r < 4; ++r) {
                int row2 = m0 + wr * 64 + mm * 16 + g * 4 + r;
                out[(size_t)row2 * DIMC + col] = acc[mm][nn][r] + bv;
            }
        }
    }
}

extern "C" void kernel_launch(void* const* d_in, const int* in_sizes, int n_in,
                              void* d_out, int out_size, void* d_ws, size_t ws_size,
                              hipStream_t stream) {
    const float* x          = (const float*)d_in[0];
    const float* mask       = (const float*)d_in[1];
    const float* qkv_w      = (const float*)d_in[2];
    const float* qkv_b      = (const float*)d_in[3];
    const float* proj_w     = (const float*)d_in[4];
    const float* proj_b     = (const float*)d_in[5];
    const float* bias_table = (const float*)d_in[6];
    const int*   rel_idx    = (const int*)d_in[7];
    float* out = (float*)d_out;

    const size_t QKV_BYTES = (size_t)16384 * 3 * 3136 * 2;   // 308,281,344
    const size_t XB_BYTES  = (size_t)100352 * 512 * 2;       // 102,760,448
    const size_t WQ_BYTES  = (size_t)1536 * 512 * 2;
    const size_t WP_BYTES  = (size_t)512 * 512 * 2;
    const size_t BM_BYTES  = (size_t)1024 * 112 * 100 * 4;   // 45,875,200 (aliases xb)

    unsigned short* qkvbuf = (unsigned short*)d_ws;
    const size_t need = QKV_BYTES + XB_BYTES + WQ_BYTES + WP_BYTES;

    if (ws_size >= need) {
        unsigned short* xb  = (unsigned short*)((char*)d_ws + QKV_BYTES);
        unsigned short* wqb = xb + (size_t)100352 * 512;
        unsigned short* wpb = wqb + (size_t)1536 * 512;
        float* bm_t = (float*)xb;   // alias: xb is dead once k_qkv2 completes

        k_cvt<<<dim3(25088), dim3(256), 0, stream>>>(x, xb, 6422528);
        k_cvt<<<dim3(384),   dim3(256), 0, stream>>>(qkv_w, wqb, 98304);
        k_cvt<<<dim3(128),   dim3(256), 0, stream>>>(proj_w, wpb, 32768);

        k_qkv2<<<dim3(9408), dim3(256), 0, stream>>>(xb, wqb, qkv_b, qkvbuf);
        k_bm<<<dim3(1024), dim3(256), 0, stream>>>(bias_table, rel_idx, mask, bm_t);
        k_attn<<<dim3(16384), dim3(448), 0, stream>>>(qkvbuf, bm_t);
        k_proj2<<<dim3(3136), dim3(256), 0, stream>>>(qkvbuf, wpb, proj_b, out);
    } else {
        float* bias_full = (float*)((char*)d_ws + QKV_BYTES);
        k_bias<<<dim3(16, 98), dim3(128), 0, stream>>>(bias_table, rel_idx, bias_full);
        k_qkv_old<<<dim3(784, 12), dim3(256), 0, stream>>>(x, qkv_w, qkv_b, qkvbuf);
        k_attn_old<<<dim3(16384), dim3(448), 0, stream>>>(qkvbuf, mask, bias_full);
        k_proj_old<<<dim3(784, 4), dim3(256), 0, stream>>>(qkvbuf, proj_w, proj_b, out);
    }
}

// Round 4
// 699.964 us; speedup vs baseline: 1.4093x; 1.0496x over previous
//
#include <hip/hip_runtime.h>
#include <hip/hip_bf16.h>
#include <stdint.h>

#define DIMC 512
#define NTOK 98
// M_TOTAL = 1024*98 = 100352 = 784 * 128

typedef float f32x4 __attribute__((ext_vector_type(4)));
typedef short bf16x8 __attribute__((ext_vector_type(8)));

__device__ inline unsigned short f2bf(float f) {
    union { float f; uint32_t u; } v; v.f = f;
    uint32_t r = v.u + 0x7fffu + ((v.u >> 16) & 1u);
    return (unsigned short)(r >> 16);
}

__device__ inline bf16x8 cvt8(float4 a, float4 b) {
    bf16x8 r;
    r[0] = (short)f2bf(a.x); r[1] = (short)f2bf(a.y);
    r[2] = (short)f2bf(a.z); r[3] = (short)f2bf(a.w);
    r[4] = (short)f2bf(b.x); r[5] = (short)f2bf(b.y);
    r[6] = (short)f2bf(b.z); r[7] = (short)f2bf(b.w);
    return r;
}

__device__ __forceinline__ void gload16(const void* g, void* l) {
    __builtin_amdgcn_global_load_lds(
        (const __attribute__((address_space(1))) unsigned int*)g,
        (__attribute__((address_space(3))) unsigned int*)l, 16, 0, 0);
}

// ---------------- fp32 -> bf16 streaming convert (8 elems/thread) --------------
__global__ void k_cvt(const float* __restrict__ src, unsigned short* __restrict__ dst,
                      int n8) {
    int i = blockIdx.x * blockDim.x + threadIdx.x;
    if (i < n8) {
        float4 a = *(const float4*)(src + (size_t)i * 8);
        float4 b = *(const float4*)(src + (size_t)i * 8 + 4);
        *(bf16x8*)(dst + (size_t)i * 8) = cvt8(a, b);
    }
}

// ---------------- combined bias+mask table, transposed + log2e-scaled ----------
__global__ void k_bm(const float* __restrict__ table, const int* __restrict__ idx,
                     const float* __restrict__ mask, float* __restrict__ bm_t) {
    int slice = blockIdx.x;            // 0..1023 = b64*16 + h
    int b64 = slice >> 4, h = slice & 15;
    float* dst = bm_t + (size_t)slice * 11200;   // 112*100
    const float* mp = mask + (size_t)b64 * 9604;
    for (int t = threadIdx.x; t < 11200; t += blockDim.x) {
        int c = t / 100, i = t - c * 100;
        float v = -1e9f;
        if (c < NTOK && i < NTOK)
            v = (table[idx[i * NTOK + c] * 16 + h] + mp[i * NTOK + c])
                * 1.4426950408889634f;
        dst[t] = v;
    }
}

// ================= qkv GEMM: 128^2 tile, 2-phase double-buffered staging =======
__global__ __launch_bounds__(256)
void k_qkv2(const unsigned short* __restrict__ xb, const unsigned short* __restrict__ wb,
            const float* __restrict__ qb, unsigned short* __restrict__ qkvbuf) {
    __shared__ unsigned short As[2][128 * 32];
    __shared__ unsigned short Bs[2][128 * 32];
    const int tid = threadIdx.x;
    const int id = blockIdx.x;
    const int xcd = id & 7, local = id >> 3;
    const int mt = xcd * 98 + local / 12;
    const int nt = local - (local / 12) * 12;
    const int m0 = mt * 128, n0 = nt * 128;
    const int wid = tid >> 6, l = tid & 63;
    const int wr = wid >> 1, wc = wid & 1;
    const int g = l >> 4, li = l & 15;

    const int r0 = tid >> 2, c0 = (tid & 3) * 8;
    const int r1 = (256 + tid) >> 2, c1 = (tid & 3) * 8;
    const unsigned short* a0p = xb + (size_t)(m0 + r0) * DIMC + c0;
    const unsigned short* a1p = xb + (size_t)(m0 + r1) * DIMC + c1;
    const unsigned short* b0p = wb + (size_t)(n0 + r0) * DIMC + c0;
    const unsigned short* b1p = wb + (size_t)(n0 + r1) * DIMC + c1;
    const int soff = wid * 512;   // wave slice (64 rows x 8 cols) in elems

    f32x4 acc[4][4] = {};

#define QSTAGE(buf, k0) do {                       \
        gload16(a0p + (k0), &As[buf][soff]);       \
        gload16(a1p + (k0), &As[buf][2048 + soff]);\
        gload16(b0p + (k0), &Bs[buf][soff]);       \
        gload16(b1p + (k0), &Bs[buf][2048 + soff]);} while (0)

#define QCOMPUTE(buf) do {                                                      \
        bf16x8 af[4], bfr[4];                                                   \
        _Pragma("unroll")                                                       \
        for (int mm = 0; mm < 4; ++mm)                                          \
            af[mm] = *(bf16x8*)&As[buf][(wr * 64 + mm * 16 + li) * 32 + g * 8]; \
        _Pragma("unroll")                                                       \
        for (int nn = 0; nn < 4; ++nn)                                          \
            bfr[nn] = *(bf16x8*)&Bs[buf][(wc * 64 + nn * 16 + li) * 32 + g * 8];\
        _Pragma("unroll")                                                       \
        for (int mm = 0; mm < 4; ++mm)                                          \
            _Pragma("unroll")                                                   \
            for (int nn = 0; nn < 4; ++nn)                                      \
                acc[mm][nn] = __builtin_amdgcn_mfma_f32_16x16x32_bf16(          \
                    af[mm], bfr[nn], acc[mm][nn], 0, 0, 0);                     } while (0)

    // prologue: tile 0 into buf0
    QSTAGE(0, 0);
    __syncthreads();

    // 16 K-steps, 2 per iteration; tile t lives in buf (t&1).
    for (int t = 0; t < 16; t += 2) {
        QSTAGE(1, (t + 1) * 32);    // stage t+1 BEFORE computing t (latency overlap)
        QCOMPUTE(0);
        __syncthreads();
        if (t + 2 < 16) QSTAGE(0, (t + 2) * 32);
        QCOMPUTE(1);
        __syncthreads();
    }
#undef QSTAGE
#undef QCOMPUTE

    #pragma unroll
    for (int mm = 0; mm < 4; ++mm) {
        #pragma unroll
        for (int nn = 0; nn < 4; ++nn) {
            int col = n0 + wc * 64 + nn * 16 + li;
            int which = col >> 9;
            int h = (col >> 5) & 15;
            int d = col & 31;
            float bv = qb[col];
            #pragma unroll
            for (int r = 0; r < 4; ++r) {
                int row = m0 + wr * 64 + mm * 16 + g * 4 + r;
                unsigned bw = (unsigned)row / 98u;
                unsigned nn_ = (unsigned)row - bw * 98u;
                float v = acc[mm][nn][r] + bv;
                // fold softmax scale AND log2e into q
                if (which == 0) v *= 0.17677669529663689f * 1.4426950408889634f;
                qkvbuf[(size_t)((bw * 16u + h) * 3u + which) * 3136u + nn_ * 32u + d] =
                    f2bf(v);
            }
        }
    }
}

// ================= proj GEMM: 2-phase double-buffered, A gathered ==============
__global__ __launch_bounds__(256)
void k_proj2(const unsigned short* __restrict__ qkvbuf,
             const unsigned short* __restrict__ wb,
             const float* __restrict__ pb, float* __restrict__ out) {
    __shared__ unsigned short As[2][128 * 32];
    __shared__ unsigned short Bs[2][128 * 32];
    const int tid = threadIdx.x;
    const int id = blockIdx.x;
    const int xcd = id & 7, local = id >> 3;
    const int mt = xcd * 98 + local / 4;
    const int nt = local & 3;
    const int m0 = mt * 128, n0 = nt * 128;
    const int wid = tid >> 6, l = tid & 63;
    const int wr = wid >> 1, wc = wid & 1;
    const int g = l >> 4, li = l & 15;

    const int r0 = tid >> 2, c0 = (tid & 3) * 8;
    const int r1 = (256 + tid) >> 2, c1 = (tid & 3) * 8;
    unsigned row0 = m0 + r0, row1 = m0 + r1;
    unsigned bw0 = row0 / 98u, nn0 = row0 - bw0 * 98u;
    unsigned bw1 = row1 / 98u, nn1 = row1 - bw1 * 98u;
    const unsigned short* a0p = qkvbuf + (size_t)bw0 * 150528u + nn0 * 32u + c0;
    const unsigned short* a1p = qkvbuf + (size_t)bw1 * 150528u + nn1 * 32u + c1;
    const unsigned short* b0p = wb + (size_t)(n0 + r0) * DIMC + c0;
    const unsigned short* b1p = wb + (size_t)(n0 + r1) * DIMC + c1;
    const int soff = wid * 512;

    f32x4 acc[4][4] = {};

#define PSTAGE(buf, t) do {                                     \
        gload16(a0p + (size_t)(t) * 9408u, &As[buf][soff]);     \
        gload16(a1p + (size_t)(t) * 9408u, &As[buf][2048 + soff]);\
        gload16(b0p + (t) * 32, &Bs[buf][soff]);                \
        gload16(b1p + (t) * 32, &Bs[buf][2048 + soff]);         } while (0)

#define PCOMPUTE(buf) do {                                                      \
        bf16x8 af[4], bfr[4];                                                   \
        _Pragma("unroll")                                                       \
        for (int mm = 0; mm < 4; ++mm)                                          \
            af[mm] = *(bf16x8*)&As[buf][(wr * 64 + mm * 16 + li) * 32 + g * 8]; \
        _Pragma("unroll")                                                       \
        for (int nn = 0; nn < 4; ++nn)                                          \
            bfr[nn] = *(bf16x8*)&Bs[buf][(wc * 64 + nn * 16 + li) * 32 + g * 8];\
        _Pragma("unroll")                                                       \
        for (int mm = 0; mm < 4; ++mm)                                          \
            _Pragma("unroll")                                                   \
            for (int nn = 0; nn < 4; ++nn)                                      \
                acc[mm][nn] = __builtin_amdgcn_mfma_f32_16x16x32_bf16(          \
                    af[mm], bfr[nn], acc[mm][nn], 0, 0, 0);                     } while (0)

    PSTAGE(0, 0);
    __syncthreads();

    for (int t = 0; t < 16; t += 2) {
        PSTAGE(1, t + 1);
        PCOMPUTE(0);
        __syncthreads();
        if (t + 2 < 16) PSTAGE(0, t + 2);
        PCOMPUTE(1);
        __syncthreads();
    }
#undef PSTAGE
#undef PCOMPUTE

    #pragma unroll
    for (int mm = 0; mm < 4; ++mm) {
        #pragma unroll
        for (int nn = 0; nn < 4; ++nn) {
            int col = n0 + wc * 64 + nn * 16 + li;
            float bv = pb[col];
            #pragma unroll
            for (int r = 0; r < 4; ++r) {
                int row2 = m0 + wr * 64 + mm * 16 + g * 4 + r;
                out[(size_t)row2 * DIMC + col] = acc[mm][nn][r] + bv;
            }
        }
    }
}

// ---------------- attention: one block per (window b, head h) -------------------
__global__ __launch_bounds__(448)
void k_attn(unsigned short* __restrict__ qkvbuf, const float* __restrict__ bm_t) {
    __shared__ short Ks[112][36];
    __shared__ short Vt[32][132];
    __shared__ short Ps[7][16][132];

    const int tid = threadIdx.x;
    const int w = tid >> 6, l = tid & 63, g = l >> 4, li = l & 15;
    const int bh = blockIdx.x;
    const int slice = bh & 1023;      // (b%64)*16 + h

    unsigned short* qslot = qkvbuf + (size_t)bh * 3 * 3136;
    const unsigned short* kslot = qslot + 3136;
    const unsigned short* vslot = qslot + 6272;

    // ---- issue all global loads up front (latency hides under staging) ----
    const float* bmp = bm_t + (size_t)slice * 11200 + (16 * w + g * 4);
    f32x4 bmf[7];
    #pragma unroll
    for (int j = 0; j < 7; ++j)
        bmf[j] = *(const f32x4*)(bmp + (16 * j + li) * 100);

    bf16x8 aq = *(const bf16x8*)(qslot + (16 * w + li) * 32 + g * 8);

    if (tid < 392) {
        int row = tid >> 2, seg = (tid & 3) * 8;
        bf16x8 kv = *(const bf16x8*)(kslot + row * 32 + seg);
        *(bf16x8*)&Ks[row][seg] = kv;
        bf16x8 vv = *(const bf16x8*)(vslot + row * 32 + seg);
        #pragma unroll
        for (int j = 0; j < 8; ++j) Vt[seg + j][row] = vv[j];
    }
    Ks[98 + (tid >> 5)][tid & 31] = 0;
    for (int t2 = tid; t2 < 32 * 34; t2 += 448) {
        int d = t2 / 34, c = t2 % 34;
        Vt[d][98 + c] = 0;
    }
    for (int t2 = l; t2 < 16 * 20; t2 += 64) {
        int r = t2 / 20, c = t2 % 20;
        Ps[w][r][112 + c] = 0;
    }

    __syncthreads();

    // S = q@K^T + bias + mask  (bias/mask as C-operand; scale+log2e folded in q)
    f32x4 s[7];
    __builtin_amdgcn_s_setprio(1);
    #pragma unroll
    for (int j = 0; j < 7; ++j) {
        bf16x8 bk = *(bf16x8*)&Ks[16 * j + li][g * 8];
        s[j] = __builtin_amdgcn_mfma_f32_16x16x32_bf16(aq, bk, bmf[j], 0, 0, 0);
    }
    __builtin_amdgcn_s_setprio(0);

    // softmax: pads carry -1e9 bias -> exp2 -> 0, no masking branches
    float sinv[4];
    #pragma unroll
    for (int r = 0; r < 4; ++r) {
        float mx = s[0][r];
        #pragma unroll
        for (int j = 1; j < 7; ++j) mx = fmaxf(mx, s[j][r]);
        mx = fmaxf(mx, __shfl_xor(mx, 1));
        mx = fmaxf(mx, __shfl_xor(mx, 2));
        mx = fmaxf(mx, __shfl_xor(mx, 4));
        mx = fmaxf(mx, __shfl_xor(mx, 8));
        float sum = 0.f;
        #pragma unroll
        for (int j = 0; j < 7; ++j) {
            float p = exp2f(s[j][r] - mx);
            sum += p;
            Ps[w][g * 4 + r][16 * j + li] = (short)f2bf(p);
        }
        sum += __shfl_xor(sum, 1);
        sum += __shfl_xor(sum, 2);
        sum += __shfl_xor(sum, 4);
        sum += __shfl_xor(sum, 8);
        sinv[r] = 1.0f / sum;
    }

    __syncthreads();

    f32x4 o[2] = {};
    __builtin_amdgcn_s_setprio(1);
    #pragma unroll
    for (int ks = 0; ks < 4; ++ks) {
        bf16x8 pa = *(bf16x8*)&Ps[w][li][ks * 32 + g * 8];
        #pragma unroll
        for (int ct = 0; ct < 2; ++ct) {
            bf16x8 vb = *(bf16x8*)&Vt[ct * 16 + li][ks * 32 + g * 8];
            o[ct] = __builtin_amdgcn_mfma_f32_16x16x32_bf16(pa, vb, o[ct], 0, 0, 0);
        }
    }
    __builtin_amdgcn_s_setprio(0);

    #pragma unroll
    for (int ct = 0; ct < 2; ++ct) {
        #pragma unroll
        for (int r = 0; r < 4; ++r) {
            int i = 16 * w + g * 4 + r;
            if (i < NTOK) {
                int d = ct * 16 + li;
                qslot[i * 32 + d] = f2bf(o[ct][r] * sinv[r]);
            }
        }
    }
}

// ================= fallback (round-1) path =====================================
__global__ void k_bias(const float* __restrict__ table, const int* __restrict__ idx,
                       float* __restrict__ bias_full) {
    int h = blockIdx.x, i = blockIdx.y, j = threadIdx.x;
    if (j < NTOK)
        bias_full[(h * NTOK + i) * NTOK + j] = table[idx[i * NTOK + j] * 16 + h];
}

__global__ __launch_bounds__(256)
void k_qkv_old(const float* __restrict__ x, const float* __restrict__ w,
               const float* __restrict__ qb, unsigned short* __restrict__ qkvbuf) {
    __shared__ short As[128][36];
    __shared__ short Bs[128][36];
    const int tid = threadIdx.x;
    const int m0 = blockIdx.x * 128, n0 = blockIdx.y * 128;
    const int wid = tid >> 6, l = tid & 63;
    const int wr = wid >> 1, wc = wid & 1;
    const int g = l >> 4, li = l & 15;
    const int srow = tid >> 1, scol = (tid & 1) * 16;

    f32x4 acc[4][4] = {};
    const float* ap = x + (size_t)(m0 + srow) * DIMC + scol;
    const float* bp = w + (size_t)(n0 + srow) * DIMC + scol;

    for (int k0 = 0; k0 < DIMC; k0 += 32) {
        float4 a0 = *(const float4*)(ap + k0);
        float4 a1 = *(const float4*)(ap + k0 + 4);
        float4 a2 = *(const float4*)(ap + k0 + 8);
        float4 a3 = *(const float4*)(ap + k0 + 12);
        float4 b0 = *(const float4*)(bp + k0);
        float4 b1 = *(const float4*)(bp + k0 + 4);
        float4 b2 = *(const float4*)(bp + k0 + 8);
        float4 b3 = *(const float4*)(bp + k0 + 12);
        *(bf16x8*)&As[srow][scol]     = cvt8(a0, a1);
        *(bf16x8*)&As[srow][scol + 8] = cvt8(a2, a3);
        *(bf16x8*)&Bs[srow][scol]     = cvt8(b0, b1);
        *(bf16x8*)&Bs[srow][scol + 8] = cvt8(b2, b3);
        __syncthreads();
        bf16x8 af[4], bfr[4];
        #pragma unroll
        for (int mm = 0; mm < 4; ++mm)
            af[mm] = *(bf16x8*)&As[wr * 64 + mm * 16 + li][g * 8];
        #pragma unroll
        for (int nn = 0; nn < 4; ++nn)
            bfr[nn] = *(bf16x8*)&Bs[wc * 64 + nn * 16 + li][g * 8];
        #pragma unroll
        for (int mm = 0; mm < 4; ++mm)
            #pragma unroll
            for (int nn = 0; nn < 4; ++nn)
                acc[mm][nn] = __builtin_amdgcn_mfma_f32_16x16x32_bf16(
                    af[mm], bfr[nn], acc[mm][nn], 0, 0, 0);
        __syncthreads();
    }

    #pragma unroll
    for (int mm = 0; mm < 4; ++mm) {
        #pragma unroll
        for (int nn = 0; nn < 4; ++nn) {
            int col = n0 + wc * 64 + nn * 16 + li;
            int which = col >> 9;
            int h = (col >> 5) & 15;
            int d = col & 31;
            float bv = qb[col];
            #pragma unroll
            for (int r = 0; r < 4; ++r) {
                int row = m0 + wr * 64 + mm * 16 + g * 4 + r;
                unsigned bw = (unsigned)row / 98u;
                unsigned nn_ = (unsigned)row - bw * 98u;
                float v = acc[mm][nn][r] + bv;
                if (which == 0) v *= 0.17677669529663689f;
                qkvbuf[(size_t)((bw * 16u + h) * 3u + which) * 3136u + nn_ * 32u + d] =
                    f2bf(v);
            }
        }
    }
}

__global__ __launch_bounds__(448)
void k_attn_old(unsigned short* __restrict__ qkvbuf, const float* __restrict__ mask,
                const float* __restrict__ bias_full) {
    __shared__ short Ks[112][36];
    __shared__ short Vt[32][132];
    __shared__ short Ps[7][16][132];

    const int tid = threadIdx.x;
    const int w = tid >> 6, l = tid & 63, g = l >> 4, li = l & 15;
    const int bh = blockIdx.x;
    const int b = bh >> 4, h = bh & 15;

    unsigned short* qslot = qkvbuf + (size_t)bh * 3 * 3136;
    const unsigned short* kslot = qslot + 3136;
    const unsigned short* vslot = qslot + 6272;

    if (tid < 392) {
        int row = tid >> 2, seg = (tid & 3) * 8;
        bf16x8 kv = *(const bf16x8*)(kslot + row * 32 + seg);
        *(bf16x8*)&Ks[row][seg] = kv;
        bf16x8 vv = *(const bf16x8*)(vslot + row * 32 + seg);
        #pragma unroll
        for (int j = 0; j < 8; ++j) Vt[seg + j][row] = vv[j];
    }
    Ks[98 + (tid >> 5)][tid & 31] = 0;
    for (int t2 = tid; t2 < 32 * 34; t2 += 448) {
        int d = t2 / 34, c = t2 % 34;
        Vt[d][98 + c] = 0;
    }
    for (int t2 = l; t2 < 16 * 20; t2 += 64) {
        int r = t2 / 20, c = t2 % 20;
        Ps[w][r][112 + c] = 0;
    }

    bf16x8 aq = *(const bf16x8*)(qslot + (16 * w + li) * 32 + g * 8);

    __syncthreads();

    f32x4 s[7];
    #pragma unroll
    for (int j = 0; j < 7; ++j) {
        bf16x8 bk = *(bf16x8*)&Ks[16 * j + li][g * 8];
        f32x4 z = {};
        s[j] = __builtin_amdgcn_mfma_f32_16x16x32_bf16(aq, bk, z, 0, 0, 0);
    }

    const float* bp = bias_full + h * 9604;
    const float* mp = mask + (b & 63) * 9604;
    float sinv[4];
    #pragma unroll
    for (int r = 0; r < 4; ++r) {
        int i = 16 * w + g * 4 + r;
        bool rowok = (i < NTOK);
        float sv[7];
        float mx = -1e30f;
        #pragma unroll
        for (int j = 0; j < 7; ++j) {
            int col = 16 * j + li;
            float t = s[j][r];
            if (rowok && col < NTOK) t += bp[i * NTOK + col] + mp[i * NTOK + col];
            else t = -1e30f;
            sv[j] = t;
            mx = fmaxf(mx, t);
        }
        mx = fmaxf(mx, __shfl_xor(mx, 1));
        mx = fmaxf(mx, __shfl_xor(mx, 2));
        mx = fmaxf(mx, __shfl_xor(mx, 4));
        mx = fmaxf(mx, __shfl_xor(mx, 8));
        float sum = 0.f;
        #pragma unroll
        for (int j = 0; j < 7; ++j) {
            float p = __expf(sv[j] - mx);
            sum += p;
            Ps[w][g * 4 + r][16 * j + li] = (short)f2bf(p);
        }
        sum += __shfl_xor(sum, 1);
        sum += __shfl_xor(sum, 2);
        sum += __shfl_xor(sum, 4);
        sum += __shfl_xor(sum, 8);
        sinv[r] = 1.0f / sum;
    }

    __syncthreads();

    f32x4 o[2] = {};
    #pragma unroll
    for (int ks = 0; ks < 4; ++ks) {
        bf16x8 pa = *(bf16x8*)&Ps[w][li][ks * 32 + g * 8];
        #pragma unroll
        for (int ct = 0; ct < 2; ++ct) {
            bf16x8 vb = *(bf16x8*)&Vt[ct * 16 + li][ks * 32 + g * 8];
            o[ct] = __builtin_amdgcn_mfma_f32_16x16x32_bf16(pa, vb, o[ct], 0, 0, 0);
        }
    }

    #pragma unroll
    for (int ct = 0; ct < 2; ++ct) {
        #pragma unroll
        for (int r = 0; r < 4; ++r) {
            int i = 16 * w + g * 4 + r;
            if (i < NTOK) {
                int d = ct * 16 + li;
                qslot[i * 32 + d] = f2bf(o[ct][r] * sinv[r]);
            }
        }
    }
}

__global__ __launch_bounds__(256)
void k_proj_old(const unsigned short* __restrict__ qkvbuf, const float* __restrict__ w,
                const float* __restrict__ pb, float* __restrict__ out) {
    __shared__ short As[128][36];
    __shared__ short Bs[128][36];
    const int tid = threadIdx.x;
    const int m0 = blockIdx.x * 128, n0 = blockIdx.y * 128;
    const int wid = tid >> 6, l = tid & 63;
    const int wr = wid >> 1, wc = wid & 1;
    const int g = l >> 4, li = l & 15;
    const int srow = tid >> 1, scol = (tid & 1) * 16;

    unsigned row = m0 + srow;
    unsigned bw = row / 98u, nn_ = row - bw * 98u;
    const unsigned short* abase =
        qkvbuf + (size_t)bw * 48u * 3136u + (size_t)nn_ * 32u + scol;
    const float* bp = w + (size_t)(n0 + srow) * DIMC + scol;

    f32x4 acc[4][4] = {};

    for (int k0 = 0; k0 < DIMC; k0 += 32) {
        int hh = k0 >> 5;
        const unsigned short* ap = abase + (size_t)hh * 9408u;
        bf16x8 A0 = *(const bf16x8*)ap;
        bf16x8 A1 = *(const bf16x8*)(ap + 8);
        float4 b0 = *(const float4*)(bp + k0);
        float4 b1 = *(const float4*)(bp + k0 + 4);
        float4 b2 = *(const float4*)(bp + k0 + 8);
        float4 b3 = *(const float4*)(bp + k0 + 12);
        *(bf16x8*)&As[srow][scol]     = A0;
        *(bf16x8*)&As[srow][scol + 8] = A1;
        *(bf16x8*)&Bs[srow][scol]     = cvt8(b0, b1);
        *(bf16x8*)&Bs[srow][scol + 8] = cvt8(b2, b3);
        __syncthreads();
        bf16x8 af[4], bfr[4];
        #pragma unroll
        for (int mm = 0; mm < 4; ++mm)
            af[mm] = *(bf16x8*)&As[wr * 64 + mm * 16 + li][g * 8];
        #pragma unroll
        for (int nn = 0; nn < 4; ++nn)
            bfr[nn] = *(bf16x8*)&Bs[wc * 64 + nn * 16 + li][g * 8];
        #pragma unroll
        for (int mm = 0; mm < 4; ++mm)
            #pragma unroll
            for (int nn = 0; nn < 4; ++nn)
                acc[mm][nn] = __builtin_amdgcn_mfma_f32_16x16x32_bf16(
                    af[mm], bfr[nn], acc[mm][nn], 0, 0, 0);
        __syncthreads();
    }

    #pragma unroll
    for (int mm = 0; mm < 4; ++mm) {
        #pragma unroll
        for (int nn = 0; nn < 4; ++nn) {
            int col = n0 + wc * 64 + nn * 16 + li;
            float bv = pb[col];
            #pragma unroll
            for (int r = 0; r < 4; ++r) {
                int row2 = m0 + wr * 64 + mm * 16 + g * 4 + r;
                out[(size_t)row2 * DIMC + col] = acc[mm][nn][r] + bv;
            }
        }
    }
}

extern "C" void kernel_launch(void* const* d_in, const int* in_sizes, int n_in,
                              void* d_out, int out_size, void* d_ws, size_t ws_size,
                              hipStream_t stream) {
    const float* x          = (const float*)d_in[0];
    const float* mask       = (const float*)d_in[1];
    const float* qkv_w      = (const float*)d_in[2];
    const float* qkv_b      = (const float*)d_in[3];
    const float* proj_w     = (const float*)d_in[4];
    const float* proj_b     = (const float*)d_in[5];
    const float* bias_table = (const float*)d_in[6];
    const int*   rel_idx    = (const int*)d_in[7];
    float* out = (float*)d_out;

    const size_t QKV_BYTES = (size_t)16384 * 3 * 3136 * 2;   // 308,281,344
    const size_t XB_BYTES  = (size_t)100352 * 512 * 2;       // 102,760,448
    const size_t WQ_BYTES  = (size_t)1536 * 512 * 2;
    const size_t WP_BYTES  = (size_t)512 * 512 * 2;

    unsigned short* qkvbuf = (unsigned short*)d_ws;
    const size_t need = QKV_BYTES + XB_BYTES + WQ_BYTES + WP_BYTES;

    if (ws_size >= need) {
        unsigned short* xb  = (unsigned short*)((char*)d_ws + QKV_BYTES);
        unsigned short* wqb = xb + (size_t)100352 * 512;
        unsigned short* wpb = wqb + (size_t)1536 * 512;
        float* bm_t = (float*)xb;   // alias: xb is dead once k_qkv2 completes

        k_cvt<<<dim3(25088), dim3(256), 0, stream>>>(x, xb, 6422528);
        k_cvt<<<dim3(384),   dim3(256), 0, stream>>>(qkv_w, wqb, 98304);
        k_cvt<<<dim3(128),   dim3(256), 0, stream>>>(proj_w, wpb, 32768);

        k_qkv2<<<dim3(9408), dim3(256), 0, stream>>>(xb, wqb, qkv_b, qkvbuf);
        k_bm<<<dim3(1024), dim3(256), 0, stream>>>(bias_table, rel_idx, mask, bm_t);
        k_attn<<<dim3(16384), dim3(448), 0, stream>>>(qkvbuf, bm_t);
        k_proj2<<<dim3(3136), dim3(256), 0, stream>>>(qkvbuf, wpb, proj_b, out);
    } else {
        float* bias_full = (float*)((char*)d_ws + QKV_BYTES);
        k_bias<<<dim3(16, 98), dim3(128), 0, stream>>>(bias_table, rel_idx, bias_full);
        k_qkv_old<<<dim3(784, 12), dim3(256), 0, stream>>>(x, qkv_w, qkv_b, qkvbuf);
        k_attn_old<<<dim3(16384), dim3(448), 0, stream>>>(qkvbuf, mask, bias_full);
        k_proj_old<<<dim3(784, 4), dim3(256), 0, stream>>>(qkvbuf, proj_w, proj_b, out);
    }
}

// Round 5
// 657.591 us; speedup vs baseline: 1.5001x; 1.0644x over previous
//
#include <hip/hip_runtime.h>
#include <hip/hip_bf16.h>
#include <stdint.h>

#define DIMC 512
#define NTOK 98
// M_TOTAL = 1024*98 = 100352 = 392 * 256

typedef float f32x4 __attribute__((ext_vector_type(4)));
typedef short bf16x8 __attribute__((ext_vector_type(8)));

__device__ inline unsigned short f2bf(float f) {
    union { float f; uint32_t u; } v; v.f = f;
    uint32_t r = v.u + 0x7fffu + ((v.u >> 16) & 1u);
    return (unsigned short)(r >> 16);
}

__device__ inline bf16x8 cvt8(float4 a, float4 b) {
    bf16x8 r;
    r[0] = (short)f2bf(a.x); r[1] = (short)f2bf(a.y);
    r[2] = (short)f2bf(a.z); r[3] = (short)f2bf(a.w);
    r[4] = (short)f2bf(b.x); r[5] = (short)f2bf(b.y);
    r[6] = (short)f2bf(b.z); r[7] = (short)f2bf(b.w);
    return r;
}

__device__ __forceinline__ void gload16(const void* g, void* l) {
    __builtin_amdgcn_global_load_lds(
        (const __attribute__((address_space(1))) unsigned int*)g,
        (__attribute__((address_space(3))) unsigned int*)l, 16, 0, 0);
}

#define CFENCE() __asm__ __volatile__("" ::: "memory")
#define BARRIER() do { CFENCE(); __builtin_amdgcn_s_barrier(); CFENCE(); } while (0)

// ---------------- fp32 -> bf16 streaming convert (8 elems/thread) --------------
__global__ void k_cvt(const float* __restrict__ src, unsigned short* __restrict__ dst,
                      int n8) {
    int i = blockIdx.x * blockDim.x + threadIdx.x;
    if (i < n8) {
        float4 a = *(const float4*)(src + (size_t)i * 8);
        float4 b = *(const float4*)(src + (size_t)i * 8 + 4);
        *(bf16x8*)(dst + (size_t)i * 8) = cvt8(a, b);
    }
}

// ---------------- combined bias+mask table, transposed + log2e-scaled ----------
__global__ void k_bm(const float* __restrict__ table, const int* __restrict__ idx,
                     const float* __restrict__ mask, float* __restrict__ bm_t) {
    int slice = blockIdx.x;            // 0..1023 = b64*16 + h
    int b64 = slice >> 4, h = slice & 15;
    float* dst = bm_t + (size_t)slice * 11200;   // 112*100
    const float* mp = mask + (size_t)b64 * 9604;
    for (int t = threadIdx.x; t < 11200; t += blockDim.x) {
        int c = t / 100, i = t - c * 100;
        float v = -1e9f;
        if (c < NTOK && i < NTOK)
            v = (table[idx[i * NTOK + c] * 16 + h] + mp[i * NTOK + c])
                * 1.4426950408889634f;
        dst[t] = v;
    }
}

// ============ qkv GEMM: 256^2 tile, BK=64, 8 waves, counted-vmcnt pipeline =====
__global__ __launch_bounds__(512, 2)
void k_qkv3(const unsigned short* __restrict__ xb, const unsigned short* __restrict__ wb,
            const float* __restrict__ qb, unsigned short* __restrict__ qkvbuf) {
    __shared__ unsigned short As[2][2][128 * 64];   // [slot][half][row*64 + col]
    __shared__ unsigned short Bs[2][2][128 * 64];
    const int tid = threadIdx.x;
    const int wid = tid >> 6, l = tid & 63, g = l >> 4, li = l & 15;
    const int wm = wid >> 2, wn = wid & 3;
    const int id = blockIdx.x;                     // 2352 = 8 * 49 * 6
    const int xcd = id & 7, local = id >> 3;
    const int mt = xcd * 49 + local / 6;
    const int nt = local - (local / 6) * 6;
    const int m0 = mt * 256, n0 = nt * 256;

    // ---- staging geometry: chunk c = i*512+tid -> row = c>>3, colgrp = c&7.
    // pre-swizzled global source: logical colgrp = phys ^ (row&7) (involution)
    const int srow = tid >> 3;
    const int scg  = tid & 7;
    const int sxor = (scg ^ (srow & 7)) * 8;       // elems
    const unsigned short* aG[2][2];
    const unsigned short* bG[2][2];
    #pragma unroll
    for (int h = 0; h < 2; ++h) {
        aG[h][0] = xb + (size_t)(m0 + h * 128 + srow) * DIMC + sxor;
        aG[h][1] = xb + (size_t)(m0 + h * 128 + 64 + srow) * DIMC + sxor;
        bG[h][0] = wb + (size_t)(n0 + h * 128 + srow) * DIMC + sxor;
        bG[h][1] = wb + (size_t)(n0 + h * 128 + 64 + srow) * DIMC + sxor;
    }
    const int lb0 = wid * 512;          // LDS elem base, chunk-set 0 (wave-uniform)
    const int lb1 = 4096 + wid * 512;   // chunk-set 1

    // ---- fragment read offsets (swizzled, loop-invariant) ----
    const int axor0 = ((0 + g) ^ (li & 7)) * 8;   // k=0 col-group
    const int axor1 = ((4 + g) ^ (li & 7)) * 8;   // k=1 col-group
    const int arow = li * 64;
    const int brow = (wn & 1) * 4096 + li * 64;
    const int bh = wn >> 1;

    f32x4 acc[8][4] = {};

#define STAGE(s, kt) do {                                   \
        gload16(aG[0][0] + (kt) * 64, &As[s][0][lb0]);      \
        gload16(aG[0][1] + (kt) * 64, &As[s][0][lb1]);      \
        gload16(aG[1][0] + (kt) * 64, &As[s][1][lb0]);      \
        gload16(aG[1][1] + (kt) * 64, &As[s][1][lb1]);      \
        gload16(bG[0][0] + (kt) * 64, &Bs[s][0][lb0]);      \
        gload16(bG[0][1] + (kt) * 64, &Bs[s][0][lb1]);      \
        gload16(bG[1][0] + (kt) * 64, &Bs[s][1][lb0]);      \
        gload16(bG[1][1] + (kt) * 64, &Bs[s][1][lb1]);      } while (0)

    STAGE(0, 0);
    #pragma unroll
    for (int kt = 0; kt < 8; ++kt) {
        const int s = kt & 1;
        if (kt < 7) {
            STAGE(s ^ 1, kt + 1);
            __asm__ __volatile__("s_waitcnt vmcnt(8)" ::: "memory");
        } else {
            __asm__ __volatile__("s_waitcnt vmcnt(0)" ::: "memory");
        }
        BARRIER();   // #1: slot-s DMAs (all waves) visible
        bf16x8 bfr[4][2];
        #pragma unroll
        for (int nq = 0; nq < 4; ++nq) {
            bfr[nq][0] = *(const bf16x8*)&Bs[s][bh][brow + nq * 1024 + axor0];
            bfr[nq][1] = *(const bf16x8*)&Bs[s][bh][brow + nq * 1024 + axor1];
        }
        #pragma unroll
        for (int q = 0; q < 4; ++q) {
            bf16x8 a00 = *(const bf16x8*)&As[s][wm][arow + (2 * q) * 1024 + axor0];
            bf16x8 a01 = *(const bf16x8*)&As[s][wm][arow + (2 * q) * 1024 + axor1];
            bf16x8 a10 = *(const bf16x8*)&As[s][wm][arow + (2 * q + 1) * 1024 + axor0];
            bf16x8 a11 = *(const bf16x8*)&As[s][wm][arow + (2 * q + 1) * 1024 + axor1];
            __builtin_amdgcn_s_setprio(1);
            #pragma unroll
            for (int nq = 0; nq < 4; ++nq) {
                acc[2 * q][nq] = __builtin_amdgcn_mfma_f32_16x16x32_bf16(
                    a00, bfr[nq][0], acc[2 * q][nq], 0, 0, 0);
                acc[2 * q][nq] = __builtin_amdgcn_mfma_f32_16x16x32_bf16(
                    a01, bfr[nq][1], acc[2 * q][nq], 0, 0, 0);
                acc[2 * q + 1][nq] = __builtin_amdgcn_mfma_f32_16x16x32_bf16(
                    a10, bfr[nq][0], acc[2 * q + 1][nq], 0, 0, 0);
                acc[2 * q + 1][nq] = __builtin_amdgcn_mfma_f32_16x16x32_bf16(
                    a11, bfr[nq][1], acc[2 * q + 1][nq], 0, 0, 0);
            }
            __builtin_amdgcn_s_setprio(0);
        }
        BARRIER();   // #2: all waves done reading slot s (safe to overwrite next iter)
    }
#undef STAGE

    #pragma unroll
    for (int mq = 0; mq < 8; ++mq) {
        #pragma unroll
        for (int nq = 0; nq < 4; ++nq) {
            int col = n0 + wn * 64 + nq * 16 + li;
            int which = col >> 9;
            int h = (col >> 5) & 15;
            int d = col & 31;
            float bv = qb[col];
            #pragma unroll
            for (int r = 0; r < 4; ++r) {
                int row = m0 + wm * 128 + mq * 16 + g * 4 + r;
                unsigned bw = (unsigned)row / 98u;
                unsigned nn_ = (unsigned)row - bw * 98u;
                float v = acc[mq][nq][r] + bv;
                if (which == 0) v *= 0.17677669529663689f * 1.4426950408889634f;
                qkvbuf[(size_t)((bw * 16u + h) * 3u + which) * 3136u + nn_ * 32u + d] =
                    f2bf(v);
            }
        }
    }
}

// ============ proj GEMM: same 256^2 pipeline, A gathered from qkvbuf ===========
__global__ __launch_bounds__(512, 2)
void k_proj3(const unsigned short* __restrict__ qkvbuf,
             const unsigned short* __restrict__ wb,
             const float* __restrict__ pb, float* __restrict__ out) {
    __shared__ unsigned short As[2][2][128 * 64];
    __shared__ unsigned short Bs[2][2][128 * 64];
    const int tid = threadIdx.x;
    const int wid = tid >> 6, l = tid & 63, g = l >> 4, li = l & 15;
    const int wm = wid >> 2, wn = wid & 3;
    const int id = blockIdx.x;                     // 784 = 8 * 49 * 2
    const int xcd = id & 7, local = id >> 3;
    const int mt = xcd * 49 + local / 2;
    const int nt = local & 1;
    const int m0 = mt * 256, n0 = nt * 256;

    const int srow = tid >> 3;
    const int scg  = tid & 7;
    const int cgx  = scg ^ (srow & 7);
    const unsigned short* aG[2][2];
    const unsigned short* bG[2][2];
    #pragma unroll
    for (int h = 0; h < 2; ++h) {
        #pragma unroll
        for (int i = 0; i < 2; ++i) {
            int R = m0 + h * 128 + i * 64 + srow;
            unsigned bw = (unsigned)R / 98u, nn = (unsigned)R - bw * 98u;
            aG[h][i] = qkvbuf + (size_t)bw * 150528u + nn * 32u
                       + (size_t)(cgx >> 2) * 9408u + (cgx & 3) * 8;
            bG[h][i] = wb + (size_t)(n0 + h * 128 + i * 64 + srow) * DIMC + cgx * 8;
        }
    }
    const int lb0 = wid * 512;
    const int lb1 = 4096 + wid * 512;

    const int axor0 = ((0 + g) ^ (li & 7)) * 8;
    const int axor1 = ((4 + g) ^ (li & 7)) * 8;
    const int arow = li * 64;
    const int brow = (wn & 1) * 4096 + li * 64;
    const int bh = wn >> 1;

    f32x4 acc[8][4] = {};

#define STAGE(s, kt) do {                                               \
        gload16(aG[0][0] + (size_t)(kt) * 18816u, &As[s][0][lb0]);      \
        gload16(aG[0][1] + (size_t)(kt) * 18816u, &As[s][0][lb1]);      \
        gload16(aG[1][0] + (size_t)(kt) * 18816u, &As[s][1][lb0]);      \
        gload16(aG[1][1] + (size_t)(kt) * 18816u, &As[s][1][lb1]);      \
        gload16(bG[0][0] + (kt) * 64, &Bs[s][0][lb0]);                  \
        gload16(bG[0][1] + (kt) * 64, &Bs[s][0][lb1]);                  \
        gload16(bG[1][0] + (kt) * 64, &Bs[s][1][lb0]);                  \
        gload16(bG[1][1] + (kt) * 64, &Bs[s][1][lb1]);                  } while (0)

    STAGE(0, 0);
    #pragma unroll
    for (int kt = 0; kt < 8; ++kt) {
        const int s = kt & 1;
        if (kt < 7) {
            STAGE(s ^ 1, kt + 1);
            __asm__ __volatile__("s_waitcnt vmcnt(8)" ::: "memory");
        } else {
            __asm__ __volatile__("s_waitcnt vmcnt(0)" ::: "memory");
        }
        BARRIER();
        bf16x8 bfr[4][2];
        #pragma unroll
        for (int nq = 0; nq < 4; ++nq) {
            bfr[nq][0] = *(const bf16x8*)&Bs[s][bh][brow + nq * 1024 + axor0];
            bfr[nq][1] = *(const bf16x8*)&Bs[s][bh][brow + nq * 1024 + axor1];
        }
        #pragma unroll
        for (int q = 0; q < 4; ++q) {
            bf16x8 a00 = *(const bf16x8*)&As[s][wm][arow + (2 * q) * 1024 + axor0];
            bf16x8 a01 = *(const bf16x8*)&As[s][wm][arow + (2 * q) * 1024 + axor1];
            bf16x8 a10 = *(const bf16x8*)&As[s][wm][arow + (2 * q + 1) * 1024 + axor0];
            bf16x8 a11 = *(const bf16x8*)&As[s][wm][arow + (2 * q + 1) * 1024 + axor1];
            __builtin_amdgcn_s_setprio(1);
            #pragma unroll
            for (int nq = 0; nq < 4; ++nq) {
                acc[2 * q][nq] = __builtin_amdgcn_mfma_f32_16x16x32_bf16(
                    a00, bfr[nq][0], acc[2 * q][nq], 0, 0, 0);
                acc[2 * q][nq] = __builtin_amdgcn_mfma_f32_16x16x32_bf16(
                    a01, bfr[nq][1], acc[2 * q][nq], 0, 0, 0);
                acc[2 * q + 1][nq] = __builtin_amdgcn_mfma_f32_16x16x32_bf16(
                    a10, bfr[nq][0], acc[2 * q + 1][nq], 0, 0, 0);
                acc[2 * q + 1][nq] = __builtin_amdgcn_mfma_f32_16x16x32_bf16(
                    a11, bfr[nq][1], acc[2 * q + 1][nq], 0, 0, 0);
            }
            __builtin_amdgcn_s_setprio(0);
        }
        BARRIER();
    }
#undef STAGE

    #pragma unroll
    for (int mq = 0; mq < 8; ++mq) {
        #pragma unroll
        for (int nq = 0; nq < 4; ++nq) {
            int col = n0 + wn * 64 + nq * 16 + li;
            float bv = pb[col];
            #pragma unroll
            for (int r = 0; r < 4; ++r) {
                int row2 = m0 + wm * 128 + mq * 16 + g * 4 + r;
                out[(size_t)row2 * DIMC + col] = acc[mq][nq][r] + bv;
            }
        }
    }
}

// ---------------- attention: one block per (window b, head h) -------------------
__global__ __launch_bounds__(448)
void k_attn(unsigned short* __restrict__ qkvbuf, const float* __restrict__ bm_t) {
    __shared__ short Ks[112][36];
    __shared__ short Vt[32][132];
    __shared__ short Ps[7][16][132];

    const int tid = threadIdx.x;
    const int w = tid >> 6, l = tid & 63, g = l >> 4, li = l & 15;
    const int bh = blockIdx.x;
    const int slice = bh & 1023;      // (b%64)*16 + h

    unsigned short* qslot = qkvbuf + (size_t)bh * 3 * 3136;
    const unsigned short* kslot = qslot + 3136;
    const unsigned short* vslot = qslot + 6272;

    const float* bmp = bm_t + (size_t)slice * 11200 + (16 * w + g * 4);
    f32x4 bmf[7];
    #pragma unroll
    for (int j = 0; j < 7; ++j)
        bmf[j] = *(const f32x4*)(bmp + (16 * j + li) * 100);

    bf16x8 aq = *(const bf16x8*)(qslot + (16 * w + li) * 32 + g * 8);

    if (tid < 392) {
        int row = tid >> 2, seg = (tid & 3) * 8;
        bf16x8 kv = *(const bf16x8*)(kslot + row * 32 + seg);
        *(bf16x8*)&Ks[row][seg] = kv;
        bf16x8 vv = *(const bf16x8*)(vslot + row * 32 + seg);
        #pragma unroll
        for (int j = 0; j < 8; ++j) Vt[seg + j][row] = vv[j];
    }
    Ks[98 + (tid >> 5)][tid & 31] = 0;
    for (int t2 = tid; t2 < 32 * 34; t2 += 448) {
        int d = t2 / 34, c = t2 % 34;
        Vt[d][98 + c] = 0;
    }
    for (int t2 = l; t2 < 16 * 20; t2 += 64) {
        int r = t2 / 20, c = t2 % 20;
        Ps[w][r][112 + c] = 0;
    }

    __syncthreads();

    f32x4 s[7];
    __builtin_amdgcn_s_setprio(1);
    #pragma unroll
    for (int j = 0; j < 7; ++j) {
        bf16x8 bk = *(bf16x8*)&Ks[16 * j + li][g * 8];
        s[j] = __builtin_amdgcn_mfma_f32_16x16x32_bf16(aq, bk, bmf[j], 0, 0, 0);
    }
    __builtin_amdgcn_s_setprio(0);

    float sinv[4];
    #pragma unroll
    for (int r = 0; r < 4; ++r) {
        float mx = s[0][r];
        #pragma unroll
        for (int j = 1; j < 7; ++j) mx = fmaxf(mx, s[j][r]);
        mx = fmaxf(mx, __shfl_xor(mx, 1));
        mx = fmaxf(mx, __shfl_xor(mx, 2));
        mx = fmaxf(mx, __shfl_xor(mx, 4));
        mx = fmaxf(mx, __shfl_xor(mx, 8));
        float sum = 0.f;
        #pragma unroll
        for (int j = 0; j < 7; ++j) {
            float p = exp2f(s[j][r] - mx);
            sum += p;
            Ps[w][g * 4 + r][16 * j + li] = (short)f2bf(p);
        }
        sum += __shfl_xor(sum, 1);
        sum += __shfl_xor(sum, 2);
        sum += __shfl_xor(sum, 4);
        sum += __shfl_xor(sum, 8);
        sinv[r] = 1.0f / sum;
    }

    __syncthreads();

    f32x4 o[2] = {};
    __builtin_amdgcn_s_setprio(1);
    #pragma unroll
    for (int ks = 0; ks < 4; ++ks) {
        bf16x8 pa = *(bf16x8*)&Ps[w][li][ks * 32 + g * 8];
        #pragma unroll
        for (int ct = 0; ct < 2; ++ct) {
            bf16x8 vb = *(bf16x8*)&Vt[ct * 16 + li][ks * 32 + g * 8];
            o[ct] = __builtin_amdgcn_mfma_f32_16x16x32_bf16(pa, vb, o[ct], 0, 0, 0);
        }
    }
    __builtin_amdgcn_s_setprio(0);

    #pragma unroll
    for (int ct = 0; ct < 2; ++ct) {
        #pragma unroll
        for (int r = 0; r < 4; ++r) {
            int i = 16 * w + g * 4 + r;
            if (i < NTOK) {
                int d = ct * 16 + li;
                qslot[i * 32 + d] = f2bf(o[ct][r] * sinv[r]);
            }
        }
    }
}

// ================= fallback (round-1) path =====================================
__global__ void k_bias(const float* __restrict__ table, const int* __restrict__ idx,
                       float* __restrict__ bias_full) {
    int h = blockIdx.x, i = blockIdx.y, j = threadIdx.x;
    if (j < NTOK)
        bias_full[(h * NTOK + i) * NTOK + j] = table[idx[i * NTOK + j] * 16 + h];
}

__global__ __launch_bounds__(256)
void k_qkv_old(const float* __restrict__ x, const float* __restrict__ w,
               const float* __restrict__ qb, unsigned short* __restrict__ qkvbuf) {
    __shared__ short As[128][36];
    __shared__ short Bs[128][36];
    const int tid = threadIdx.x;
    const int m0 = blockIdx.x * 128, n0 = blockIdx.y * 128;
    const int wid = tid >> 6, l = tid & 63;
    const int wr = wid >> 1, wc = wid & 1;
    const int g = l >> 4, li = l & 15;
    const int srow = tid >> 1, scol = (tid & 1) * 16;

    f32x4 acc[4][4] = {};
    const float* ap = x + (size_t)(m0 + srow) * DIMC + scol;
    const float* bp = w + (size_t)(n0 + srow) * DIMC + scol;

    for (int k0 = 0; k0 < DIMC; k0 += 32) {
        float4 a0 = *(const float4*)(ap + k0);
        float4 a1 = *(const float4*)(ap + k0 + 4);
        float4 a2 = *(const float4*)(ap + k0 + 8);
        float4 a3 = *(const float4*)(ap + k0 + 12);
        float4 b0 = *(const float4*)(bp + k0);
        float4 b1 = *(const float4*)(bp + k0 + 4);
        float4 b2 = *(const float4*)(bp + k0 + 8);
        float4 b3 = *(const float4*)(bp + k0 + 12);
        *(bf16x8*)&As[srow][scol]     = cvt8(a0, a1);
        *(bf16x8*)&As[srow][scol + 8] = cvt8(a2, a3);
        *(bf16x8*)&Bs[srow][scol]     = cvt8(b0, b1);
        *(bf16x8*)&Bs[srow][scol + 8] = cvt8(b2, b3);
        __syncthreads();
        bf16x8 af[4], bfr[4];
        #pragma unroll
        for (int mm = 0; mm < 4; ++mm)
            af[mm] = *(bf16x8*)&As[wr * 64 + mm * 16 + li][g * 8];
        #pragma unroll
        for (int nn = 0; nn < 4; ++nn)
            bfr[nn] = *(bf16x8*)&Bs[wc * 64 + nn * 16 + li][g * 8];
        #pragma unroll
        for (int mm = 0; mm < 4; ++mm)
            #pragma unroll
            for (int nn = 0; nn < 4; ++nn)
                acc[mm][nn] = __builtin_amdgcn_mfma_f32_16x16x32_bf16(
                    af[mm], bfr[nn], acc[mm][nn], 0, 0, 0);
        __syncthreads();
    }

    #pragma unroll
    for (int mm = 0; mm < 4; ++mm) {
        #pragma unroll
        for (int nn = 0; nn < 4; ++nn) {
            int col = n0 + wc * 64 + nn * 16 + li;
            int which = col >> 9;
            int h = (col >> 5) & 15;
            int d = col & 31;
            float bv = qb[col];
            #pragma unroll
            for (int r = 0; r < 4; ++r) {
                int row = m0 + wr * 64 + mm * 16 + g * 4 + r;
                unsigned bw = (unsigned)row / 98u;
                unsigned nn_ = (unsigned)row - bw * 98u;
                float v = acc[mm][nn][r] + bv;
                if (which == 0) v *= 0.17677669529663689f;
                qkvbuf[(size_t)((bw * 16u + h) * 3u + which) * 3136u + nn_ * 32u + d] =
                    f2bf(v);
            }
        }
    }
}

__global__ __launch_bounds__(448)
void k_attn_old(unsigned short* __restrict__ qkvbuf, const float* __restrict__ mask,
                const float* __restrict__ bias_full) {
    __shared__ short Ks[112][36];
    __shared__ short Vt[32][132];
    __shared__ short Ps[7][16][132];

    const int tid = threadIdx.x;
    const int w = tid >> 6, l = tid & 63, g = l >> 4, li = l & 15;
    const int bh = blockIdx.x;
    const int b = bh >> 4, h = bh & 15;

    unsigned short* qslot = qkvbuf + (size_t)bh * 3 * 3136;
    const unsigned short* kslot = qslot + 3136;
    const unsigned short* vslot = qslot + 6272;

    if (tid < 392) {
        int row = tid >> 2, seg = (tid & 3) * 8;
        bf16x8 kv = *(const bf16x8*)(kslot + row * 32 + seg);
        *(bf16x8*)&Ks[row][seg] = kv;
        bf16x8 vv = *(const bf16x8*)(vslot + row * 32 + seg);
        #pragma unroll
        for (int j = 0; j < 8; ++j) Vt[seg + j][row] = vv[j];
    }
    Ks[98 + (tid >> 5)][tid & 31] = 0;
    for (int t2 = tid; t2 < 32 * 34; t2 += 448) {
        int d = t2 / 34, c = t2 % 34;
        Vt[d][98 + c] = 0;
    }
    for (int t2 = l; t2 < 16 * 20; t2 += 64) {
        int r = t2 / 20, c = t2 % 20;
        Ps[w][r][112 + c] = 0;
    }

    bf16x8 aq = *(const bf16x8*)(qslot + (16 * w + li) * 32 + g * 8);

    __syncthreads();

    f32x4 s[7];
    #pragma unroll
    for (int j = 0; j < 7; ++j) {
        bf16x8 bk = *(bf16x8*)&Ks[16 * j + li][g * 8];
        f32x4 z = {};
        s[j] = __builtin_amdgcn_mfma_f32_16x16x32_bf16(aq, bk, z, 0, 0, 0);
    }

    const float* bp = bias_full + h * 9604;
    const float* mp = mask + (b & 63) * 9604;
    float sinv[4];
    #pragma unroll
    for (int r = 0; r < 4; ++r) {
        int i = 16 * w + g * 4 + r;
        bool rowok = (i < NTOK);
        float sv[7];
        float mx = -1e30f;
        #pragma unroll
        for (int j = 0; j < 7; ++j) {
            int col = 16 * j + li;
            float t = s[j][r];
            if (rowok && col < NTOK) t += bp[i * NTOK + col] + mp[i * NTOK + col];
            else t = -1e30f;
            sv[j] = t;
            mx = fmaxf(mx, t);
        }
        mx = fmaxf(mx, __shfl_xor(mx, 1));
        mx = fmaxf(mx, __shfl_xor(mx, 2));
        mx = fmaxf(mx, __shfl_xor(mx, 4));
        mx = fmaxf(mx, __shfl_xor(mx, 8));
        float sum = 0.f;
        #pragma unroll
        for (int j = 0; j < 7; ++j) {
            float p = __expf(sv[j] - mx);
            sum += p;
            Ps[w][g * 4 + r][16 * j + li] = (short)f2bf(p);
        }
        sum += __shfl_xor(sum, 1);
        sum += __shfl_xor(sum, 2);
        sum += __shfl_xor(sum, 4);
        sum += __shfl_xor(sum, 8);
        sinv[r] = 1.0f / sum;
    }

    __syncthreads();

    f32x4 o[2] = {};
    #pragma unroll
    for (int ks = 0; ks < 4; ++ks) {
        bf16x8 pa = *(bf16x8*)&Ps[w][li][ks * 32 + g * 8];
        #pragma unroll
        for (int ct = 0; ct < 2; ++ct) {
            bf16x8 vb = *(bf16x8*)&Vt[ct * 16 + li][ks * 32 + g * 8];
            o[ct] = __builtin_amdgcn_mfma_f32_16x16x32_bf16(pa, vb, o[ct], 0, 0, 0);
        }
    }

    #pragma unroll
    for (int ct = 0; ct < 2; ++ct) {
        #pragma unroll
        for (int r = 0; r < 4; ++r) {
            int i = 16 * w + g * 4 + r;
            if (i < NTOK) {
                int d = ct * 16 + li;
                qslot[i * 32 + d] = f2bf(o[ct][r] * sinv[r]);
            }
        }
    }
}

__global__ __launch_bounds__(256)
void k_proj_old(const unsigned short* __restrict__ qkvbuf, const float* __restrict__ w,
                const float* __restrict__ pb, float* __restrict__ out) {
    __shared__ short As[128][36];
    __shared__ short Bs[128][36];
    const int tid = threadIdx.x;
    const int m0 = blockIdx.x * 128, n0 = blockIdx.y * 128;
    const int wid = tid >> 6, l = tid & 63;
    const int wr = wid >> 1, wc = wid & 1;
    const int g = l >> 4, li = l & 15;
    const int srow = tid >> 1, scol = (tid & 1) * 16;

    unsigned row = m0 + srow;
    unsigned bw = row / 98u, nn_ = row - bw * 98u;
    const unsigned short* abase =
        qkvbuf + (size_t)bw * 48u * 3136u + (size_t)nn_ * 32u + scol;
    const float* bp = w + (size_t)(n0 + srow) * DIMC + scol;

    f32x4 acc[4][4] = {};

    for (int k0 = 0; k0 < DIMC; k0 += 32) {
        int hh = k0 >> 5;
        const unsigned short* ap = abase + (size_t)hh * 9408u;
        bf16x8 A0 = *(const bf16x8*)ap;
        bf16x8 A1 = *(const bf16x8*)(ap + 8);
        float4 b0 = *(const float4*)(bp + k0);
        float4 b1 = *(const float4*)(bp + k0 + 4);
        float4 b2 = *(const float4*)(bp + k0 + 8);
        float4 b3 = *(const float4*)(bp + k0 + 12);
        *(bf16x8*)&As[srow][scol]     = A0;
        *(bf16x8*)&As[srow][scol + 8] = A1;
        *(bf16x8*)&Bs[srow][scol]     = cvt8(b0, b1);
        *(bf16x8*)&Bs[srow][scol + 8] = cvt8(b2, b3);
        __syncthreads();
        bf16x8 af[4], bfr[4];
        #pragma unroll
        for (int mm = 0; mm < 4; ++mm)
            af[mm] = *(bf16x8*)&As[wr * 64 + mm * 16 + li][g * 8];
        #pragma unroll
        for (int nn = 0; nn < 4; ++nn)
            bfr[nn] = *(bf16x8*)&Bs[wc * 64 + nn * 16 + li][g * 8];
        #pragma unroll
        for (int mm = 0; mm < 4; ++mm)
            #pragma unroll
            for (int nn = 0; nn < 4; ++nn)
                acc[mm][nn] = __builtin_amdgcn_mfma_f32_16x16x32_bf16(
                    af[mm], bfr[nn], acc[mm][nn], 0, 0, 0);
        __syncthreads();
    }

    #pragma unroll
    for (int mm = 0; mm < 4; ++mm) {
        #pragma unroll
        for (int nn = 0; nn < 4; ++nn) {
            int col = n0 + wc * 64 + nn * 16 + li;
            float bv = pb[col];
            #pragma unroll
            for (int r = 0; r < 4; ++r) {
                int row2 = m0 + wr * 64 + mm * 16 + g * 4 + r;
                out[(size_t)row2 * DIMC + col] = acc[mm][nn][r] + bv;
            }
        }
    }
}

extern "C" void kernel_launch(void* const* d_in, const int* in_sizes, int n_in,
                              void* d_out, int out_size, void* d_ws, size_t ws_size,
                              hipStream_t stream) {
    const float* x          = (const float*)d_in[0];
    const float* mask       = (const float*)d_in[1];
    const float* qkv_w      = (const float*)d_in[2];
    const float* qkv_b      = (const float*)d_in[3];
    const float* proj_w     = (const float*)d_in[4];
    const float* proj_b     = (const float*)d_in[5];
    const float* bias_table = (const float*)d_in[6];
    const int*   rel_idx    = (const int*)d_in[7];
    float* out = (float*)d_out;

    const size_t QKV_BYTES = (size_t)16384 * 3 * 3136 * 2;   // 308,281,344
    const size_t XB_BYTES  = (size_t)100352 * 512 * 2;       // 102,760,448
    const size_t WQ_BYTES  = (size_t)1536 * 512 * 2;
    const size_t WP_BYTES  = (size_t)512 * 512 * 2;

    unsigned short* qkvbuf = (unsigned short*)d_ws;
    const size_t need = QKV_BYTES + XB_BYTES + WQ_BYTES + WP_BYTES;

    if (ws_size >= need) {
        unsigned short* xb  = (unsigned short*)((char*)d_ws + QKV_BYTES);
        unsigned short* wqb = xb + (size_t)100352 * 512;
        unsigned short* wpb = wqb + (size_t)1536 * 512;
        float* bm_t = (float*)xb;   // alias: xb is dead once k_qkv3 completes

        k_cvt<<<dim3(25088), dim3(256), 0, stream>>>(x, xb, 6422528);
        k_cvt<<<dim3(384),   dim3(256), 0, stream>>>(qkv_w, wqb, 98304);
        k_cvt<<<dim3(128),   dim3(256), 0, stream>>>(proj_w, wpb, 32768);

        k_qkv3<<<dim3(2352), dim3(512), 0, stream>>>(xb, wqb, qkv_b, qkvbuf);
        k_bm<<<dim3(1024), dim3(256), 0, stream>>>(bias_table, rel_idx, mask, bm_t);
        k_attn<<<dim3(16384), dim3(448), 0, stream>>>(qkvbuf, bm_t);
        k_proj3<<<dim3(784), dim3(512), 0, stream>>>(qkvbuf, wpb, proj_b, out);
    } else {
        float* bias_full = (float*)((char*)d_ws + QKV_BYTES);
        k_bias<<<dim3(16, 98), dim3(128), 0, stream>>>(bias_table, rel_idx, bias_full);
        k_qkv_old<<<dim3(784, 12), dim3(256), 0, stream>>>(x, qkv_w, qkv_b, qkvbuf);
        k_attn_old<<<dim3(16384), dim3(448), 0, stream>>>(qkvbuf, mask, bias_full);
        k_proj_old<<<dim3(784, 4), dim3(256), 0, stream>>>(qkvbuf, proj_w, proj_b, out);
    }
}